// Round 9
// baseline (381.216 us; speedup 1.0000x reference)
//
#include <hip/hip_runtime.h>
#include <stdint.h>

#define TT 2048
#define CC 1024

typedef short bf16x8 __attribute__((ext_vector_type(8)));
typedef float f32x4 __attribute__((ext_vector_type(4)));
typedef unsigned uint2v __attribute__((ext_vector_type(2)));
typedef __attribute__((address_space(3))) uint32_t lds_u32_t;
typedef const __attribute__((address_space(1))) uint32_t glb_u32_t;

__device__ inline unsigned short f2b(float f) {
  union { float f; unsigned u; } c; c.f = f;
  unsigned u = c.u;
  return (unsigned short)((u + 0x7fffu + ((u >> 16) & 1u)) >> 16);
}
__device__ inline float b2f(unsigned short s) {
  union { unsigned u; float f; } c; c.u = ((unsigned)s) << 16; return c.f;
}

__device__ inline void gl_lds16(const void* g, void* l) {
  glb_u32_t* gp = (glb_u32_t*)(uintptr_t)g;
  lds_u32_t* lp = (lds_u32_t*)(uint32_t)(uintptr_t)l;
  __builtin_amdgcn_global_load_lds(gp, lp, 16, 0, 0);
}

// XCD-aware swizzle (verified R3: FETCH 200->57MB on proj3). gridDim.y % 8 == 0.
__device__ inline void swiz(int& bx, int& by, int& bz) {
  int nx = gridDim.x, ny = gridDim.y;
  int flat = (blockIdx.z * ny + blockIdx.y) * nx + blockIdx.x;
  int xcd = flat & 7;
  int idx = flat >> 3;
  int perz = (nx * ny) >> 3;
  bz = idx / perz;
  int rem = idx - bz * perz;
  int r = rem / nx;
  bx = rem - r * nx;
  by = xcd * (ny >> 3) + r;
}

// ---------------- fused transposes: out[C,R] = bf16(in[R,C]), 11 segments ----------------
struct TSeg { const float* in; unsigned short* out; int R, C, tx, start; };
struct TransAll { TSeg seg[11]; int nseg; };
__global__ void transpose_all(TransAll ta) {
  __shared__ float tile[32][33];
  int bid = blockIdx.x;
  int si = 0;
  while (si + 1 < ta.nseg && bid >= ta.seg[si + 1].start) si++;
  TSeg sg = ta.seg[si];
  int lt = bid - sg.start;
  int bx = lt % sg.tx, by = lt / sg.tx;
  int c0 = bx * 32, r0 = by * 32;
  int tx = threadIdx.x, ty = threadIdx.y;  // 32x8
  for (int i = ty; i < 32; i += 8) {
    int r = r0 + i, c = c0 + tx;
    tile[i][tx] = (r < sg.R && c < sg.C) ? sg.in[(size_t)r * sg.C + c] : 0.f;
  }
  __syncthreads();
  int rr = r0 + tx;
  for (int i = ty; i < 32; i += 8) {
    int cc = c0 + i;
    if (cc < sg.C && rr < sg.R) sg.out[(size_t)cc * sg.R + rr] = f2b(tile[tx][i]);
  }
}

// ---- token shift: xb=bf16(x); xxb=bf16(shift(x)-x); xxx=bf16(x + xx*tmx) ----
__global__ void shift_mix(const float* __restrict__ x, const float* __restrict__ tmx,
                          unsigned short* __restrict__ xb, unsigned short* __restrict__ xxb,
                          unsigned short* __restrict__ xxx) {
  int idx = blockIdx.x * 256 + threadIdx.x;  // float4 groups, 2M total
  int c4 = idx & 255;
  int row = idx >> 8;
  int t = row & (TT - 1);
  const float4* x4 = (const float4*)x;
  float4 xv = x4[idx];
  float4 pv = make_float4(0.f, 0.f, 0.f, 0.f);
  if (t > 0) pv = x4[idx - 256];
  float4 d;
  d.x = pv.x - xv.x; d.y = pv.y - xv.y; d.z = pv.z - xv.z; d.w = pv.w - xv.w;
  ushort4 ob;
  ob.x = f2b(xv.x); ob.y = f2b(xv.y); ob.z = f2b(xv.z); ob.w = f2b(xv.w);
  ((ushort4*)xb)[idx] = ob;
  ushort4 od;
  od.x = f2b(d.x); od.y = f2b(d.y); od.z = f2b(d.z); od.w = f2b(d.w);
  ((ushort4*)xxb)[idx] = od;
  float4 tm = ((const float4*)tmx)[c4];
  ushort4 o;
  o.x = f2b(xv.x + d.x * tm.x);
  o.y = f2b(xv.y + d.y * tm.y);
  o.z = f2b(xv.z + d.z * tm.z);
  o.w = f2b(xv.w + d.w * tm.w);
  ((ushort4*)xxx)[idx] = o;
}

// ---------------- pipelined MFMA core A: 128x128 tile, BK=32, 3 LDS stages ----------------
// Used by gemm_bf16 (decay K=64), splitk, gate4. R10 lesson: this 2-barrier
// structure wants the 128^2 tile; bigger tiles only pay with the counted-vmcnt
// schedule (core256x128 below).
// COALESCED staging (R6): one gl_lds16 covers 16 rows x 64B (lane = row*4+chunk).
// LDS slot-chunk XOR-swizzled (chunk ^ ((row>>1)&3)); conflict-free (measured 0).
__device__ __forceinline__ void gemm_core_pipe(
    const unsigned short* __restrict__ A, const unsigned short* __restrict__ Bt,
    int k0beg, int k0end, int lda, int ldb, int rowBase, int colBase,
    unsigned short* As, unsigned short* Bs, f32x4 acc[4][4], int w, int lane,
    int quad, int l16, int waveM, int waveN) {
#pragma unroll
  for (int i = 0; i < 4; i++)
#pragma unroll
    for (int j = 0; j < 4; j++) acc[i][j] = (f32x4){0.f, 0.f, 0.f, 0.f};
  const int SSB = 8192;  // bytes per stage (128 rows x 64 B)
  const int nIter = (k0end - k0beg) >> 5;
  int rl = lane >> 2;
  int cl = (lane & 3) ^ ((lane >> 3) & 3);
  int rA0 = w * 16 + rl, rA1 = (w + 4) * 16 + rl;
  const unsigned short* gA0 = A + (size_t)(rowBase + rA0) * lda + cl * 8 + k0beg;
  const unsigned short* gA1 = A + (size_t)(rowBase + rA1) * lda + cl * 8 + k0beg;
  const unsigned short* gB0 = Bt + (size_t)(colBase + rA0) * ldb + cl * 8 + k0beg;
  const unsigned short* gB1 = Bt + (size_t)(colBase + rA1) * ldb + cl * 8 + k0beg;
  char* dA0 = (char*)As + w * 1024;
  char* dA1 = (char*)As + (w + 4) * 1024;
  char* dB0 = (char*)Bs + w * 1024;
  char* dB1 = (char*)Bs + (w + 4) * 1024;
  int sw = quad ^ ((l16 >> 1) & 3);
  int aoff = (waveM + l16) * 64 + sw * 16;
  int boff = (waveN + l16) * 64 + sw * 16;

#define ISSUE(it, st)                               \
  {                                                 \
    int ko = (it) * 32;                             \
    gl_lds16(gA0 + ko, dA0 + (st) * SSB);           \
    gl_lds16(gA1 + ko, dA1 + (st) * SSB);           \
    gl_lds16(gB0 + ko, dB0 + (st) * SSB);           \
    gl_lds16(gB1 + ko, dB1 + (st) * SSB);           \
  }

  ISSUE(0, 0)
  if (nIter > 1) ISSUE(1, 1)
  int stage = 0;
  for (int it = 0; it < nIter; ++it) {
    if (it + 1 < nIter) {
      asm volatile("s_waitcnt vmcnt(4)\ns_barrier" ::: "memory");
    } else {
      asm volatile("s_waitcnt vmcnt(0)\ns_barrier" ::: "memory");
    }
    if (it + 2 < nIter) {
      int ns = stage + 2; if (ns >= 3) ns -= 3;
      ISSUE(it + 2, ns)
    }
    const char* Ab = (const char*)As + stage * SSB;
    const char* Bb = (const char*)Bs + stage * SSB;
    bf16x8 af[4], bfr[4];
#pragma unroll
    for (int mt = 0; mt < 4; mt++)
      af[mt] = *(const bf16x8*)(Ab + aoff + mt * 1024);
#pragma unroll
    for (int nt = 0; nt < 4; nt++)
      bfr[nt] = *(const bf16x8*)(Bb + boff + nt * 1024);
#pragma unroll
    for (int mt = 0; mt < 4; mt++)
#pragma unroll
      for (int nt = 0; nt < 4; nt++)
        acc[mt][nt] = __builtin_amdgcn_mfma_f32_16x16x32_bf16(af[mt], bfr[nt], acc[mt][nt], 0, 0, 0);
    stage = stage + 1; if (stage >= 3) stage -= 3;
  }
#undef ISSUE
}

// ---------------- generic GEMM (128x128 core): modes 0 f32, 4 decay perm ----------------
__global__ __launch_bounds__(256) void gemm_bf16(
    const unsigned short* __restrict__ A, const unsigned short* __restrict__ Bt,
    int N, int K, int lda, int ldb, int mode, int ldc,
    float* __restrict__ outF, unsigned short* __restrict__ outB,
    const float* __restrict__ tm) {
  __shared__ __align__(16) unsigned short As[3 * 4096];
  __shared__ __align__(16) unsigned short Bs[3 * 4096];
  int bx, by, bz;
  swiz(bx, by, bz);
  (void)bz;
  int tid = threadIdx.x;
  int w = tid >> 6, lane = tid & 63;
  int quad = lane >> 4, l16 = lane & 15;
  int rowBase = by * 128;
  int colBase = bx * 128;
  int waveM = (w >> 1) * 64, waveN = (w & 1) * 64;
  f32x4 acc[4][4];
  gemm_core_pipe(A, Bt, 0, K, lda, ldb, rowBase, colBase, As, Bs, acc, w, lane, quad, l16, waveM, waveN);
#pragma unroll
  for (int mt = 0; mt < 4; mt++)
#pragma unroll
    for (int nt = 0; nt < 4; nt++)
#pragma unroll
      for (int rg = 0; rg < 4; rg++) {
        int row = rowBase + waveM + mt * 16 + quad * 4 + rg;
        int col = colBase + waveN + nt * 16 + l16;
        if (col >= N) continue;
        float val = acc[mt][nt][rg];
        if (mode == 0) {
          outF[(size_t)row * ldc + col] = val;
        } else {
          int b = row >> 11, t = row & (TT - 1), h = col >> 4, n = col & 15;
          outF[(size_t)((b * 64 + h) * TT + t) * 16 + n] = expf(-expf(tm[col] + val));
        }
      }
}

// ---------------- split-K GEMM (128x128 core): partials f32 [S][M][ldp] ----------------
__global__ __launch_bounds__(256) void gemm_splitk(
    const unsigned short* __restrict__ A, const unsigned short* __restrict__ Bt,
    int N, int Kc, int lda, int ldb, int ldp, float* __restrict__ part) {
  __shared__ __align__(16) unsigned short As[3 * 4096];
  __shared__ __align__(16) unsigned short Bs[3 * 4096];
  int s = blockIdx.x, by = blockIdx.y;
  int M = gridDim.y * 128;
  int tid = threadIdx.x;
  int w = tid >> 6, lane = tid & 63;
  int quad = lane >> 4, l16 = lane & 15;
  int rowBase = by * 128;
  int waveM = (w >> 1) * 64, waveN = (w & 1) * 64;
  f32x4 acc[4][4];
  gemm_core_pipe(A, Bt, s * Kc, (s + 1) * Kc, lda, ldb, rowBase, 0, As, Bs, acc, w, lane, quad, l16, waveM, waveN);
  float* pb = part + (size_t)s * M * ldp;
#pragma unroll
  for (int mt = 0; mt < 4; mt++)
#pragma unroll
    for (int nt = 0; nt < 4; nt++)
#pragma unroll
      for (int rg = 0; rg < 4; rg++) {
        int row = rowBase + waveM + mt * 16 + quad * 4 + rg;
        int col = waveN + nt * 16 + l16;
        if (col < N) pb[(size_t)row * ldp + col] = acc[mt][nt][rg];
      }
}

// ---------------- reduce split-K partials + tanh -> bf16 ----------------
__global__ __launch_bounds__(256) void reduce_tanh(
    const float* __restrict__ part, unsigned short* __restrict__ out,
    int total4, int S, int strideElems) {
  int idx = blockIdx.x * 256 + threadIdx.x;
  if (idx >= total4) return;
  float4 a = ((const float4*)part)[idx];
  for (int s = 1; s < S; s++) {
    float4 b = ((const float4*)(part + (size_t)s * strideElems))[idx];
    a.x += b.x; a.y += b.y; a.z += b.z; a.w += b.w;
  }
  ushort4 o;
  o.x = f2b(tanhf(a.x)); o.y = f2b(tanhf(a.y));
  o.z = f2b(tanhf(a.z)); o.w = f2b(tanhf(a.w));
  ((ushort4*)out)[idx] = o;
}

// ---------------- batched gate GEMM (K=32): epilogue x + xx*(tm+acc) ----------------
struct GateArgs {
  const unsigned short* A;
  const unsigned short* Bt;
  unsigned short* out[4];
  const float* tm[4];
  const unsigned short* xb;
  const unsigned short* xxb;
};
__global__ __launch_bounds__(256) void gemm_gate4(GateArgs ga) {
  __shared__ __align__(16) unsigned short As[3 * 4096];
  __shared__ __align__(16) unsigned short Bs[3 * 4096];
  // 4 gates of the same (row,col) tile consecutive on one XCD (xb/xxb L2 reuse)
  int flat = (blockIdx.z * 64 + blockIdx.y) * 8 + blockIdx.x;
  int xcd = flat & 7;
  int idx = flat >> 3;
  int z = idx & 3;
  int tile = idx >> 2;
  int by = xcd * 8 + (tile >> 3);
  int bx = tile & 7;
  const unsigned short* A = ga.A + z * 32;
  const unsigned short* Bt = ga.Bt + (size_t)z * 1024 * 32;
  unsigned short* outB = ga.out[z];
  const float* tm = ga.tm[z];
  int tid = threadIdx.x;
  int w = tid >> 6, lane = tid & 63;
  int quad = lane >> 4, l16 = lane & 15;
  int rowBase = by * 128;
  int colBase = bx * 128;
  int waveM = (w >> 1) * 64, waveN = (w & 1) * 64;
  f32x4 acc[4][4];
  gemm_core_pipe(A, Bt, 0, 32, 128, 32, rowBase, colBase, As, Bs, acc, w, lane, quad, l16, waveM, waveN);
#pragma unroll
  for (int mt = 0; mt < 4; mt++)
#pragma unroll
    for (int nt = 0; nt < 4; nt++)
#pragma unroll
      for (int rg = 0; rg < 4; rg++) {
        int row = rowBase + waveM + mt * 16 + quad * 4 + rg;
        int col = colBase + waveN + nt * 16 + l16;
        size_t o = (size_t)row * CC + col;
        float xv = b2f(ga.xb[o]), xxv = b2f(ga.xxb[o]);
        outB[o] = f2b(xv + xxv * (tm[col] + acc[mt][nt][rg]));
      }
}

// ---------------- counted-vmcnt 256x128 core (R12; R15: 3 slots) ----------------
// R15 theory: per-half budget @1blk/CU was 1650cyc, of which MFMA demand 620
// (per SIMD: 32 MFMA x 19.4cyc) and LDS demand ~344 (88KB @256B/cyc) — the
// ~1000cyc gap is barrier/vmcnt stall with a single 8-wave block per CU.
// Shrink 4->3 slots (96->72KB LDS) => 2 blocks/CU (144KB<=160): independent
// blocks' barriers decorrelate, one block's MFMA fills the other's drain.
// Pipeline depth 3->2 halves in flight: steady vmcnt(3) (6 outstanding).
// Slot safety: stage at iter h targets slot (h+2)%3=(h-1)%3 whose reads all
// completed at h-1's lgkmcnt(0)+barrier. Grid rule: blocks multiple of 256;
// 768 at 2/CU = 1.5 rounds but the tail is 1 blk on EVERY CU (soft).
__device__ __forceinline__ void core256x128(
    const unsigned short* __restrict__ A, const unsigned short* __restrict__ Bt,
    int rowBase, int colBase, unsigned short* As, unsigned short* Bs,
    f32x4 acc[4][4]) {
  int tid = threadIdx.x;
  int w = tid >> 6, lane = tid & 63;
  int quad = lane >> 4, l16 = lane & 15;
  int wr = w >> 1, wc = w & 1;
  int rl = lane >> 2;
  int cl = (lane & 3) ^ ((lane >> 3) & 3);
  const unsigned short* gA0 = A + (size_t)(rowBase + w * 16 + rl) * 1024 + cl * 8;
  const unsigned short* gA1 = A + (size_t)(rowBase + (w + 8) * 16 + rl) * 1024 + cl * 8;
  const unsigned short* gB0 = Bt + (size_t)(colBase + w * 16 + rl) * 1024 + cl * 8;
  char* dA0 = (char*)As + w * 1024;
  char* dA1 = (char*)As + (w + 8) * 1024;
  char* dB0 = (char*)Bs + w * 1024;
  int sw = quad ^ ((l16 >> 1) & 3);
  int aoffB = wr * 4096 + l16 * 64 + sw * 16;
  int boffB = wc * 4096 + l16 * 64 + sw * 16;
#pragma unroll
  for (int i = 0; i < 4; i++)
#pragma unroll
    for (int j = 0; j < 4; j++) acc[i][j] = (f32x4){0.f, 0.f, 0.f, 0.f};

#define STG(h, st)                                        \
  { int kc = (h) * 32;                                    \
    int slA = (st) * 16384, slB = (st) * 8192;            \
    gl_lds16(gA0 + kc, dA0 + slA);                        \
    gl_lds16(gA1 + kc, dA1 + slA);                        \
    gl_lds16(gB0 + kc, dB0 + slB); }

  STG(0, 0) STG(1, 1)
  asm volatile("s_waitcnt vmcnt(3)\ns_barrier" ::: "memory");  // half 0 landed

  int sl = 0;
  for (int h = 0; h < 32; ++h) {
    const char* Ab = (const char*)As + sl * 16384;
    const char* Bb = (const char*)Bs + sl * 8192;
    bf16x8 af[4], bfr[4];
#pragma unroll
    for (int nt = 0; nt < 4; nt++)
      bfr[nt] = *(const bf16x8*)(Bb + boffB + nt * 1024);
#pragma unroll
    for (int mt = 0; mt < 4; mt++)
      af[mt] = *(const bf16x8*)(Ab + aoffB + mt * 1024);
    if (h + 2 < 32) {
      int ns = sl + 2; if (ns >= 3) ns -= 3;
      STG(h + 2, ns)
    }
    __builtin_amdgcn_s_setprio(1);
#pragma unroll
    for (int mt = 0; mt < 4; mt++)
#pragma unroll
      for (int nt = 0; nt < 4; nt++)
        acc[mt][nt] = __builtin_amdgcn_mfma_f32_16x16x32_bf16(af[mt], bfr[nt], acc[mt][nt], 0, 0, 0);
    __builtin_amdgcn_s_setprio(0);
    // counted wait (own-wave loads), then barrier publishes all waves' halves.
    // steady outstanding after STG(h+2): halves {h+1,h+2} = 6 -> vmcnt(3).
    if (h <= 29) {
      asm volatile("s_waitcnt vmcnt(3) lgkmcnt(0)\ns_barrier" ::: "memory");
    } else if (h == 30) {
      asm volatile("s_waitcnt vmcnt(0) lgkmcnt(0)\ns_barrier" ::: "memory");
    }
    sl = sl + 1; if (sl >= 3) sl = 0;
  }
#undef STG
}

// ---------------- projection GEMM (counted-vmcnt core, perm bf16 store) ----------------
struct ProjArgs {
  const unsigned short* A[3];
  const unsigned short* Bt[3];
  unsigned short* out[3];
};
__global__ __launch_bounds__(512, 4) void gemm_proj3_8ph(ProjArgs pa) {
  __shared__ __align__(16) unsigned short As[3 * 8192];  // 3 slots x 16KB
  __shared__ __align__(16) unsigned short Bs[3 * 4096];  // 3 slots x 8KB
  int bx, by, bz;
  swiz(bx, by, bz);
  f32x4 acc[4][4];
  core256x128(pa.A[bz], pa.Bt[bz], by * 256, bx * 128, As, Bs, acc);
  unsigned short* outB = pa.out[bz];
  int tid = threadIdx.x;
  int w = tid >> 6, lane = tid & 63;
  int quad = lane >> 4, l16 = lane & 15;
  int wr = w >> 1, wc = w & 1;
#pragma unroll
  for (int mt = 0; mt < 4; mt++)
#pragma unroll
    for (int nt = 0; nt < 4; nt++)
#pragma unroll
      for (int rg = 0; rg < 4; rg++) {
        int row = by * 256 + wr * 64 + mt * 16 + quad * 4 + rg;
        int col = bx * 128 + wc * 64 + nt * 16 + l16;
        int b = row >> 11, t = row & (TT - 1), hh = col >> 4, n = col & 15;
        outB[(size_t)((b * 64 + hh) * TT + t) * 16 + n] = f2b(acc[mt][nt][rg]);
      }
}

// ---------------- Wo GEMM (counted-vmcnt core, f32 row-major store) ----------------
// Grid (8,32) = 256 blocks; with 2-blk/CU capacity all blocks resident at once.
__global__ __launch_bounds__(512, 4) void gemm_wo_8ph(
    const unsigned short* __restrict__ A, const unsigned short* __restrict__ Bt,
    float* __restrict__ outF) {
  __shared__ __align__(16) unsigned short As[3 * 8192];
  __shared__ __align__(16) unsigned short Bs[3 * 4096];
  int bx, by, bz;
  swiz(bx, by, bz);
  (void)bz;
  f32x4 acc[4][4];
  core256x128(A, Bt, by * 256, bx * 128, As, Bs, acc);
  int tid = threadIdx.x;
  int w = tid >> 6, lane = tid & 63;
  int quad = lane >> 4, l16 = lane & 15;
  int wr = w >> 1, wc = w & 1;
#pragma unroll
  for (int mt = 0; mt < 4; mt++)
#pragma unroll
    for (int nt = 0; nt < 4; nt++)
#pragma unroll
      for (int rg = 0; rg < 4; rg++) {
        int row = by * 256 + wr * 64 + mt * 16 + quad * 4 + rg;
        int col = bx * 128 + wc * 64 + nt * 16 + l16;
        outF[(size_t)row * CC + col] = acc[mt][nt][rg];
      }
}

// ---------------- WKV6 chunk-parallel scan (16 waves per (b,h)) ----------------
// R8 version (R13's direct-global traded DS pipe for per-step global LATENCY,
// 102us — LDS staging amortizes latency to one coalesced load per 16-step tile).
// (a) r/k/v bf16 in LDS (b64/u16 reads; conversions on idle VALU pipe);
//     w stays f32 (128-long decay product chain).
// (b) cross-p output reduction via permlane{32,16}_swap (VALU) not __shfl_xor
//     (DS). permlaneN_swap returns {new_d, new_s}; needed element is in .y.
__device__ __forceinline__ float reduce_p(float part) {
#if __has_builtin(__builtin_amdgcn_permlane32_swap) && __has_builtin(__builtin_amdgcn_permlane16_swap)
  uint2v a = __builtin_amdgcn_permlane32_swap(__float_as_uint(part), __float_as_uint(part), false, false);
  float s1 = part + __uint_as_float(a.y);
  uint2v b = __builtin_amdgcn_permlane16_swap(__float_as_uint(s1), __float_as_uint(s1), false, false);
  return s1 + __uint_as_float(b.y);
#else
  part += __shfl_xor(part, 16, 64);
  part += __shfl_xor(part, 32, 64);
  return part;
#endif
}

__global__ __launch_bounds__(1024) void wkv_scan2(
    const unsigned short* __restrict__ r, const unsigned short* __restrict__ k,
    const unsigned short* __restrict__ v, const float* __restrict__ wd,
    const float* __restrict__ u, float* __restrict__ y) {
  __shared__ __align__(16) unsigned short lrb[16][256];
  __shared__ __align__(16) unsigned short lkb[16][256];
  __shared__ __align__(16) unsigned short lvb[16][256];
  __shared__ __align__(16) float lw[16][256];
  __shared__ __align__(16) float Lend[16][256];
  __shared__ __align__(16) float Sini[16][256];
  __shared__ float Eend[16][16];
  int bh = blockIdx.x;
  int b = bh >> 6, h = bh & 63;
  int tid = threadIdx.x;
  int c = tid >> 6, lane = tid & 63;
  int j = lane & 15, p = lane >> 4;
  size_t base = (size_t)bh * TT * 16 + (size_t)c * 128 * 16;

  float S0 = 0.f, S1 = 0.f, S2 = 0.f, S3 = 0.f;
  float E0 = 1.f, E1 = 1.f, E2 = 1.f, E3 = 1.f;
  for (int t0 = 0; t0 < 128; t0 += 16) {
    size_t off = base + (size_t)t0 * 16;
    ushort4 kv4 = ((const ushort4*)(k + off))[lane];
    ushort4 vv = ((const ushort4*)(v + off))[lane];
    float4 wv = ((const float4*)(wd + off))[lane];
    ((ushort4*)lkb[c])[lane] = kv4;
    ((ushort4*)lvb[c])[lane] = vv;
    ((float4*)lw[c])[lane] = wv;
#pragma unroll
    for (int s = 0; s < 16; s++) {
      ushort4 kk = *(const ushort4*)(lkb[c] + s * 16 + p * 4);
      float4 ww = *(const float4*)(lw[c] + s * 16 + p * 4);
      float vj = b2f(lvb[c][s * 16 + j]);
      S0 = fmaf(ww.x, S0, b2f(kk.x) * vj); E0 *= ww.x;
      S1 = fmaf(ww.y, S1, b2f(kk.y) * vj); E1 *= ww.y;
      S2 = fmaf(ww.z, S2, b2f(kk.z) * vj); E2 *= ww.z;
      S3 = fmaf(ww.w, S3, b2f(kk.w) * vj); E3 *= ww.w;
    }
  }
  Lend[c][(p * 4 + 0) * 16 + j] = S0;
  Lend[c][(p * 4 + 1) * 16 + j] = S1;
  Lend[c][(p * 4 + 2) * 16 + j] = S2;
  Lend[c][(p * 4 + 3) * 16 + j] = S3;
  if (j == 0) {
    Eend[c][p * 4 + 0] = E0;
    Eend[c][p * 4 + 1] = E1;
    Eend[c][p * 4 + 2] = E2;
    Eend[c][p * 4 + 3] = E3;
  }
  __syncthreads();

  if (c == 0) {
    float T0 = 0.f, T1 = 0.f, T2 = 0.f, T3 = 0.f;
    for (int cc = 0; cc < 16; cc++) {
      Sini[cc][(p * 4 + 0) * 16 + j] = T0;
      Sini[cc][(p * 4 + 1) * 16 + j] = T1;
      Sini[cc][(p * 4 + 2) * 16 + j] = T2;
      Sini[cc][(p * 4 + 3) * 16 + j] = T3;
      float e0 = Eend[cc][p * 4 + 0], e1 = Eend[cc][p * 4 + 1];
      float e2 = Eend[cc][p * 4 + 2], e3 = Eend[cc][p * 4 + 3];
      T0 = fmaf(e0, T0, Lend[cc][(p * 4 + 0) * 16 + j]);
      T1 = fmaf(e1, T1, Lend[cc][(p * 4 + 1) * 16 + j]);
      T2 = fmaf(e2, T2, Lend[cc][(p * 4 + 2) * 16 + j]);
      T3 = fmaf(e3, T3, Lend[cc][(p * 4 + 3) * 16 + j]);
    }
  }
  __syncthreads();

  float u0 = u[h * 16 + p * 4 + 0], u1 = u[h * 16 + p * 4 + 1];
  float u2 = u[h * 16 + p * 4 + 2], u3 = u[h * 16 + p * 4 + 3];
  S0 = Sini[c][(p * 4 + 0) * 16 + j];
  S1 = Sini[c][(p * 4 + 1) * 16 + j];
  S2 = Sini[c][(p * 4 + 2) * 16 + j];
  S3 = Sini[c][(p * 4 + 3) * 16 + j];
  for (int t0 = 0; t0 < 128; t0 += 16) {
    size_t off = base + (size_t)t0 * 16;
    ushort4 rv = ((const ushort4*)(r + off))[lane];
    ushort4 kv4 = ((const ushort4*)(k + off))[lane];
    ushort4 vv = ((const ushort4*)(v + off))[lane];
    float4 wv = ((const float4*)(wd + off))[lane];
    ((ushort4*)lrb[c])[lane] = rv;
    ((ushort4*)lkb[c])[lane] = kv4;
    ((ushort4*)lvb[c])[lane] = vv;
    ((float4*)lw[c])[lane] = wv;
#pragma unroll
    for (int s = 0; s < 16; s++) {
      ushort4 rr4 = *(const ushort4*)(lrb[c] + s * 16 + p * 4);
      ushort4 kk4 = *(const ushort4*)(lkb[c] + s * 16 + p * 4);
      float4 ww = *(const float4*)(lw[c] + s * 16 + p * 4);
      float vj = b2f(lvb[c][s * 16 + j]);
      float kv, part;
      kv = b2f(kk4.x) * vj; part = b2f(rr4.x) * fmaf(u0, kv, S0); S0 = fmaf(ww.x, S0, kv);
      kv = b2f(kk4.y) * vj; part = fmaf(b2f(rr4.y), fmaf(u1, kv, S1), part); S1 = fmaf(ww.y, S1, kv);
      kv = b2f(kk4.z) * vj; part = fmaf(b2f(rr4.z), fmaf(u2, kv, S2), part); S2 = fmaf(ww.z, S2, kv);
      kv = b2f(kk4.w) * vj; part = fmaf(b2f(rr4.w), fmaf(u3, kv, S3), part); S3 = fmaf(ww.w, S3, kv);
      float tot = reduce_p(part);
      if (p == 0) y[(size_t)(b * TT + c * 128 + t0 + s) * CC + h * 16 + j] = tot;
    }
  }
}

// ---------------- LayerNorm -> bf16 ----------------
__global__ __launch_bounds__(256) void ln_fused(const float* __restrict__ y,
                                                const float* __restrict__ g,
                                                const float* __restrict__ be,
                                                unsigned short* __restrict__ out) {
  int row = blockIdx.x;
  int tid = threadIdx.x;
  float4 val = ((const float4*)(y + (size_t)row * CC))[tid];
  float s = val.x + val.y + val.z + val.w;
  float sq = val.x * val.x + val.y * val.y + val.z * val.z + val.w * val.w;
#pragma unroll
  for (int m = 1; m < 64; m <<= 1) {
    s += __shfl_xor(s, m, 64);
    sq += __shfl_xor(sq, m, 64);
  }
  __shared__ float ss[4], s2[4];
  int w = tid >> 6;
  if ((tid & 63) == 0) { ss[w] = s; s2[w] = sq; }
  __syncthreads();
  s = ss[0] + ss[1] + ss[2] + ss[3];
  sq = s2[0] + s2[1] + s2[2] + s2[3];
  float mu = s * (1.f / 1024.f);
  float var = sq * (1.f / 1024.f) - mu * mu;
  float rstd = rsqrtf(var + 1e-5f);
  float4 gg = ((const float4*)g)[tid];
  float4 bb = ((const float4*)be)[tid];
  ushort4 o;
  o.x = f2b((val.x - mu) * rstd * gg.x + bb.x);
  o.y = f2b((val.y - mu) * rstd * gg.y + bb.y);
  o.z = f2b((val.z - mu) * rstd * gg.z + bb.z);
  o.w = f2b((val.w - mu) * rstd * gg.w + bb.w);
  ((ushort4*)(out + (size_t)row * CC))[tid] = o;
}

extern "C" void kernel_launch(void* const* d_in, const int* in_sizes, int n_in,
                              void* d_out, int out_size, void* d_ws, size_t ws_size,
                              hipStream_t stream) {
  (void)in_sizes; (void)n_in; (void)out_size; (void)ws_size;
  const float* x = (const float*)d_in[0];
  const float* tmx = (const float*)d_in[1];
  const float* tmw = (const float*)d_in[2];
  const float* tmk = (const float*)d_in[3];
  const float* tmv = (const float*)d_in[4];
  const float* tmr = (const float*)d_in[5];
  const float* w1 = (const float*)d_in[6];
  const float* w2 = (const float*)d_in[7];
  const float* tdecay = (const float*)d_in[8];
  const float* dw1 = (const float*)d_in[9];
  const float* dw2 = (const float*)d_in[10];
  const float* faaaa = (const float*)d_in[11];
  const float* Wr = (const float*)d_in[12];
  const float* Wk = (const float*)d_in[13];
  const float* Wv = (const float*)d_in[14];
  const float* Wo = (const float*)d_in[15];
  const float* lng = (const float*)d_in[16];
  const float* lnb = (const float*)d_in[17];
  float* out = (float*)d_out;

  char* ws = (char*)d_ws;
  const size_t MBy = 1ull << 20;
  unsigned short* rb   = (unsigned short*)(ws + 0);        // 16MB bf16 [BH,T,16]
  unsigned short* kbuf = (unsigned short*)(ws + 16 * MBy); // 16MB
  unsigned short* vbuf = (unsigned short*)(ws + 32 * MBy); // 16MB
  float* wdb = (float*)(ws + 48 * MBy);                    // 32MB f32 [BH,T,16]
  unsigned short* xb    = (unsigned short*)(ws + 80 * MBy);  // 16MB (dead after gates)
  unsigned short* xxb16 = (unsigned short*)(ws + 96 * MBy);  // 16MB (dead after gates)
  float* yb = (float*)(ws + 80 * MBy);                       // 32MB, aliases xb+xxb16
  unsigned short* xxxb = (unsigned short*)(ws + 112 * MBy);  // 16MB (dead after mixer)
  unsigned short* xwb  = (unsigned short*)(ws + 112 * MBy);  // aliases xxx
  unsigned short* xrb  = (unsigned short*)(ws + 128 * MBy);  // 16MB
  unsigned short* xkb  = (unsigned short*)(ws + 144 * MBy);  // 16MB (dead after proj)
  unsigned short* ynb  = (unsigned short*)(ws + 144 * MBy);  // aliases xkb
  unsigned short* xvb  = (unsigned short*)(ws + 160 * MBy);  // 16MB
  // split-K partial scratch, placed in regions dead at their use time:
  float* mixP  = (float*)(ws + 128 * MBy);  // 16MB f32 [4][8192][128]; xrb written later
  float* decP  = (float*)(ws + 0);          // 8MB  f32 [4][8192][64];  rb written later
  unsigned short* mtmpb = (unsigned short*)(ws + 176 * MBy); // 2MB bf16 [8192,128]
  unsigned short* dtmpb = (unsigned short*)(ws + 178 * MBy); // 1MB bf16 [8192,64]
  char* wreg = ws + 179 * MBy;
  unsigned short* w1t  = (unsigned short*)(wreg);               // [128,1024]
  unsigned short* w2t  = (unsigned short*)(wreg + 256 * 1024);  // 4x[1024,32]
  unsigned short* dw1t = (unsigned short*)(wreg + 512 * 1024);  // [64,1024] (+pad reads ok)
  unsigned short* dw2t = (unsigned short*)(wreg + 768 * 1024);  // [1024,64]
  unsigned short* Wrt  = (unsigned short*)(wreg + 1024 * 1024); // [1024,1024]
  unsigned short* Wkt = Wrt + 1024 * 1024;
  unsigned short* Wvt = Wkt + 1024 * 1024;
  unsigned short* Wot = Wvt + 1024 * 1024;

  dim3 tb(32, 8);
  {
    TransAll ta;
    int st = 0, si = 0;
    auto add = [&](const float* in, unsigned short* o, int R, int C) {
      int tx = (C + 31) / 32, ty = (R + 31) / 32;
      ta.seg[si++] = TSeg{in, o, R, C, tx, st};
      st += tx * ty;
    };
    add(Wr, Wrt, 1024, 1024);
    add(Wk, Wkt, 1024, 1024);
    add(Wv, Wvt, 1024, 1024);
    add(Wo, Wot, 1024, 1024);
    for (int g = 0; g < 4; g++)
      add(w2 + (size_t)g * 32 * 1024, w2t + (size_t)g * 1024 * 32, 32, 1024);
    add(w1, w1t, 1024, 128);
    add(dw1, dw1t, 1024, 64);
    add(dw2, dw2t, 64, 1024);
    ta.nseg = si;
    transpose_all<<<st, tb, 0, stream>>>(ta);
  }

  shift_mix<<<8192, 256, 0, stream>>>(x, tmx, xb, xxb16, xxxb);

  // mixer: mtmp = tanh(xxx @ w1) via split-K(4)
  gemm_splitk<<<dim3(4, 64), 256, 0, stream>>>(xxxb, w1t, 128, 256, 1024, 1024, 128, mixP);
  reduce_tanh<<<1024, 256, 0, stream>>>(mixP, mtmpb, 8192 * 128 / 4, 4, 8192 * 128);

  // gates (batched): xg = bf16(x + xx*(tm_g + mtmp[:,g] @ w2[g]))
  {
    GateArgs ga;
    ga.A = mtmpb; ga.Bt = w2t;
    ga.out[0] = xwb; ga.out[1] = xkb; ga.out[2] = xvb; ga.out[3] = xrb;
    ga.tm[0] = tmw; ga.tm[1] = tmk; ga.tm[2] = tmv; ga.tm[3] = tmr;
    ga.xb = xb; ga.xxb = xxb16;
    gemm_gate4<<<dim3(8, 64, 4), 256, 0, stream>>>(ga);
  }
  // decay: dtmp = tanh(xw @ dw1) via split-K(4); wd = exp(-exp(tdecay + dtmp @ dw2))
  gemm_splitk<<<dim3(4, 64), 256, 0, stream>>>(xwb, dw1t, 64, 256, 1024, 1024, 64, decP);
  reduce_tanh<<<512, 256, 0, stream>>>(decP, dtmpb, 8192 * 64 / 4, 4, 8192 * 64);
  gemm_bf16<<<dim3(8, 64), 256, 0, stream>>>(dtmpb, dw2t, 1024, 64, 64, 64, 4, 1024,
                                             wdb, nullptr, tdecay);
  // projections (batched, permuted bf16 [BH,T,16]), 256x128 counted-vmcnt tiles,
  // 768 blocks; 3-slot LDS (72KB) -> 2 blocks/CU
  {
    ProjArgs pa;
    pa.A[0] = xrb; pa.A[1] = xkb; pa.A[2] = xvb;
    pa.Bt[0] = Wrt; pa.Bt[1] = Wkt; pa.Bt[2] = Wvt;
    pa.out[0] = rb; pa.out[1] = kbuf; pa.out[2] = vbuf;
    gemm_proj3_8ph<<<dim3(8, 32, 3), 512, 0, stream>>>(pa);
  }

  wkv_scan2<<<256, 1024, 0, stream>>>(rb, kbuf, vbuf, wdb, faaaa, yb);
  ln_fused<<<8192, 256, 0, stream>>>(yb, lng, lnb, ynb);
  // out = ynorm @ W_o (counted-vmcnt core, 256 blocks)
  gemm_wo_8ph<<<dim3(8, 32), 512, 0, stream>>>(ynb, Wot, out);
}

// Round 10
// 372.651 us; speedup vs baseline: 1.0230x; 1.0230x over previous
//
#include <hip/hip_runtime.h>
#include <stdint.h>

#define TT 2048
#define CC 1024

typedef short bf16x8 __attribute__((ext_vector_type(8)));
typedef float f32x4 __attribute__((ext_vector_type(4)));
typedef unsigned uint2v __attribute__((ext_vector_type(2)));
typedef __attribute__((address_space(3))) uint32_t lds_u32_t;
typedef const __attribute__((address_space(1))) uint32_t glb_u32_t;

__device__ inline unsigned short f2b(float f) {
  union { float f; unsigned u; } c; c.f = f;
  unsigned u = c.u;
  return (unsigned short)((u + 0x7fffu + ((u >> 16) & 1u)) >> 16);
}
__device__ inline float b2f(unsigned short s) {
  union { unsigned u; float f; } c; c.u = ((unsigned)s) << 16; return c.f;
}

__device__ inline void gl_lds16(const void* g, void* l) {
  glb_u32_t* gp = (glb_u32_t*)(uintptr_t)g;
  lds_u32_t* lp = (lds_u32_t*)(uint32_t)(uintptr_t)l;
  __builtin_amdgcn_global_load_lds(gp, lp, 16, 0, 0);
}

// XCD-aware swizzle (verified R3: FETCH 200->57MB on proj3). gridDim.y % 8 == 0.
__device__ inline void swiz(int& bx, int& by, int& bz) {
  int nx = gridDim.x, ny = gridDim.y;
  int flat = (blockIdx.z * ny + blockIdx.y) * nx + blockIdx.x;
  int xcd = flat & 7;
  int idx = flat >> 3;
  int perz = (nx * ny) >> 3;
  bz = idx / perz;
  int rem = idx - bz * perz;
  int r = rem / nx;
  bx = rem - r * nx;
  by = xcd * (ny >> 3) + r;
}

// ---------------- fused transposes: out[C,R] = bf16(in[R,C]), 11 segments ----------------
struct TSeg { const float* in; unsigned short* out; int R, C, tx, start; };
struct TransAll { TSeg seg[11]; int nseg; };
__global__ void transpose_all(TransAll ta) {
  __shared__ float tile[32][33];
  int bid = blockIdx.x;
  int si = 0;
  while (si + 1 < ta.nseg && bid >= ta.seg[si + 1].start) si++;
  TSeg sg = ta.seg[si];
  int lt = bid - sg.start;
  int bx = lt % sg.tx, by = lt / sg.tx;
  int c0 = bx * 32, r0 = by * 32;
  int tx = threadIdx.x, ty = threadIdx.y;  // 32x8
  for (int i = ty; i < 32; i += 8) {
    int r = r0 + i, c = c0 + tx;
    tile[i][tx] = (r < sg.R && c < sg.C) ? sg.in[(size_t)r * sg.C + c] : 0.f;
  }
  __syncthreads();
  int rr = r0 + tx;
  for (int i = ty; i < 32; i += 8) {
    int cc = c0 + i;
    if (cc < sg.C && rr < sg.R) sg.out[(size_t)cc * sg.R + rr] = f2b(tile[tx][i]);
  }
}

// ---- token shift: xb=bf16(x); xxb=bf16(shift(x)-x); xxx=bf16(x + xx*tmx) ----
__global__ void shift_mix(const float* __restrict__ x, const float* __restrict__ tmx,
                          unsigned short* __restrict__ xb, unsigned short* __restrict__ xxb,
                          unsigned short* __restrict__ xxx) {
  int idx = blockIdx.x * 256 + threadIdx.x;  // float4 groups, 2M total
  int c4 = idx & 255;
  int row = idx >> 8;
  int t = row & (TT - 1);
  const float4* x4 = (const float4*)x;
  float4 xv = x4[idx];
  float4 pv = make_float4(0.f, 0.f, 0.f, 0.f);
  if (t > 0) pv = x4[idx - 256];
  float4 d;
  d.x = pv.x - xv.x; d.y = pv.y - xv.y; d.z = pv.z - xv.z; d.w = pv.w - xv.w;
  ushort4 ob;
  ob.x = f2b(xv.x); ob.y = f2b(xv.y); ob.z = f2b(xv.z); ob.w = f2b(xv.w);
  ((ushort4*)xb)[idx] = ob;
  ushort4 od;
  od.x = f2b(d.x); od.y = f2b(d.y); od.z = f2b(d.z); od.w = f2b(d.w);
  ((ushort4*)xxb)[idx] = od;
  float4 tm = ((const float4*)tmx)[c4];
  ushort4 o;
  o.x = f2b(xv.x + d.x * tm.x);
  o.y = f2b(xv.y + d.y * tm.y);
  o.z = f2b(xv.z + d.z * tm.z);
  o.w = f2b(xv.w + d.w * tm.w);
  ((ushort4*)xxx)[idx] = o;
}

// ---------------- pipelined MFMA core A: 128x128 tile, BK=32, 3 LDS stages ----------------
// Used by gemm_bf16 (decay K=64), splitk, gate4. R10 lesson: this 2-barrier
// structure wants the 128^2 tile; bigger tiles only pay with the counted-vmcnt
// schedule (core256x128 below).
// COALESCED staging (R6): one gl_lds16 covers 16 rows x 64B (lane = row*4+chunk).
// LDS slot-chunk XOR-swizzled (chunk ^ ((row>>1)&3)); conflict-free (measured 0).
__device__ __forceinline__ void gemm_core_pipe(
    const unsigned short* __restrict__ A, const unsigned short* __restrict__ Bt,
    int k0beg, int k0end, int lda, int ldb, int rowBase, int colBase,
    unsigned short* As, unsigned short* Bs, f32x4 acc[4][4], int w, int lane,
    int quad, int l16, int waveM, int waveN) {
#pragma unroll
  for (int i = 0; i < 4; i++)
#pragma unroll
    for (int j = 0; j < 4; j++) acc[i][j] = (f32x4){0.f, 0.f, 0.f, 0.f};
  const int SSB = 8192;  // bytes per stage (128 rows x 64 B)
  const int nIter = (k0end - k0beg) >> 5;
  int rl = lane >> 2;
  int cl = (lane & 3) ^ ((lane >> 3) & 3);
  int rA0 = w * 16 + rl, rA1 = (w + 4) * 16 + rl;
  const unsigned short* gA0 = A + (size_t)(rowBase + rA0) * lda + cl * 8 + k0beg;
  const unsigned short* gA1 = A + (size_t)(rowBase + rA1) * lda + cl * 8 + k0beg;
  const unsigned short* gB0 = Bt + (size_t)(colBase + rA0) * ldb + cl * 8 + k0beg;
  const unsigned short* gB1 = Bt + (size_t)(colBase + rA1) * ldb + cl * 8 + k0beg;
  char* dA0 = (char*)As + w * 1024;
  char* dA1 = (char*)As + (w + 4) * 1024;
  char* dB0 = (char*)Bs + w * 1024;
  char* dB1 = (char*)Bs + (w + 4) * 1024;
  int sw = quad ^ ((l16 >> 1) & 3);
  int aoff = (waveM + l16) * 64 + sw * 16;
  int boff = (waveN + l16) * 64 + sw * 16;

#define ISSUE(it, st)                               \
  {                                                 \
    int ko = (it) * 32;                             \
    gl_lds16(gA0 + ko, dA0 + (st) * SSB);           \
    gl_lds16(gA1 + ko, dA1 + (st) * SSB);           \
    gl_lds16(gB0 + ko, dB0 + (st) * SSB);           \
    gl_lds16(gB1 + ko, dB1 + (st) * SSB);           \
  }

  ISSUE(0, 0)
  if (nIter > 1) ISSUE(1, 1)
  int stage = 0;
  for (int it = 0; it < nIter; ++it) {
    if (it + 1 < nIter) {
      asm volatile("s_waitcnt vmcnt(4)\ns_barrier" ::: "memory");
    } else {
      asm volatile("s_waitcnt vmcnt(0)\ns_barrier" ::: "memory");
    }
    if (it + 2 < nIter) {
      int ns = stage + 2; if (ns >= 3) ns -= 3;
      ISSUE(it + 2, ns)
    }
    const char* Ab = (const char*)As + stage * SSB;
    const char* Bb = (const char*)Bs + stage * SSB;
    bf16x8 af[4], bfr[4];
#pragma unroll
    for (int mt = 0; mt < 4; mt++)
      af[mt] = *(const bf16x8*)(Ab + aoff + mt * 1024);
#pragma unroll
    for (int nt = 0; nt < 4; nt++)
      bfr[nt] = *(const bf16x8*)(Bb + boff + nt * 1024);
#pragma unroll
    for (int mt = 0; mt < 4; mt++)
#pragma unroll
      for (int nt = 0; nt < 4; nt++)
        acc[mt][nt] = __builtin_amdgcn_mfma_f32_16x16x32_bf16(af[mt], bfr[nt], acc[mt][nt], 0, 0, 0);
    stage = stage + 1; if (stage >= 3) stage -= 3;
  }
#undef ISSUE
}

// ---------------- generic GEMM (128x128 core): modes 0 f32, 4 decay perm ----------------
__global__ __launch_bounds__(256) void gemm_bf16(
    const unsigned short* __restrict__ A, const unsigned short* __restrict__ Bt,
    int N, int K, int lda, int ldb, int mode, int ldc,
    float* __restrict__ outF, unsigned short* __restrict__ outB,
    const float* __restrict__ tm) {
  __shared__ __align__(16) unsigned short As[3 * 4096];
  __shared__ __align__(16) unsigned short Bs[3 * 4096];
  int bx, by, bz;
  swiz(bx, by, bz);
  (void)bz;
  int tid = threadIdx.x;
  int w = tid >> 6, lane = tid & 63;
  int quad = lane >> 4, l16 = lane & 15;
  int rowBase = by * 128;
  int colBase = bx * 128;
  int waveM = (w >> 1) * 64, waveN = (w & 1) * 64;
  f32x4 acc[4][4];
  gemm_core_pipe(A, Bt, 0, K, lda, ldb, rowBase, colBase, As, Bs, acc, w, lane, quad, l16, waveM, waveN);
#pragma unroll
  for (int mt = 0; mt < 4; mt++)
#pragma unroll
    for (int nt = 0; nt < 4; nt++)
#pragma unroll
      for (int rg = 0; rg < 4; rg++) {
        int row = rowBase + waveM + mt * 16 + quad * 4 + rg;
        int col = colBase + waveN + nt * 16 + l16;
        if (col >= N) continue;
        float val = acc[mt][nt][rg];
        if (mode == 0) {
          outF[(size_t)row * ldc + col] = val;
        } else {
          int b = row >> 11, t = row & (TT - 1), h = col >> 4, n = col & 15;
          outF[(size_t)((b * 64 + h) * TT + t) * 16 + n] = expf(-expf(tm[col] + val));
        }
      }
}

// ---------------- split-K GEMM (128x128 core): partials f32 [S][M][ldp] ----------------
__global__ __launch_bounds__(256) void gemm_splitk(
    const unsigned short* __restrict__ A, const unsigned short* __restrict__ Bt,
    int N, int Kc, int lda, int ldb, int ldp, float* __restrict__ part) {
  __shared__ __align__(16) unsigned short As[3 * 4096];
  __shared__ __align__(16) unsigned short Bs[3 * 4096];
  int s = blockIdx.x, by = blockIdx.y;
  int M = gridDim.y * 128;
  int tid = threadIdx.x;
  int w = tid >> 6, lane = tid & 63;
  int quad = lane >> 4, l16 = lane & 15;
  int rowBase = by * 128;
  int waveM = (w >> 1) * 64, waveN = (w & 1) * 64;
  f32x4 acc[4][4];
  gemm_core_pipe(A, Bt, s * Kc, (s + 1) * Kc, lda, ldb, rowBase, 0, As, Bs, acc, w, lane, quad, l16, waveM, waveN);
  float* pb = part + (size_t)s * M * ldp;
#pragma unroll
  for (int mt = 0; mt < 4; mt++)
#pragma unroll
    for (int nt = 0; nt < 4; nt++)
#pragma unroll
      for (int rg = 0; rg < 4; rg++) {
        int row = rowBase + waveM + mt * 16 + quad * 4 + rg;
        int col = waveN + nt * 16 + l16;
        if (col < N) pb[(size_t)row * ldp + col] = acc[mt][nt][rg];
      }
}

// ---------------- reduce split-K partials + tanh -> bf16 ----------------
__global__ __launch_bounds__(256) void reduce_tanh(
    const float* __restrict__ part, unsigned short* __restrict__ out,
    int total4, int S, int strideElems) {
  int idx = blockIdx.x * 256 + threadIdx.x;
  if (idx >= total4) return;
  float4 a = ((const float4*)part)[idx];
  for (int s = 1; s < S; s++) {
    float4 b = ((const float4*)(part + (size_t)s * strideElems))[idx];
    a.x += b.x; a.y += b.y; a.z += b.z; a.w += b.w;
  }
  ushort4 o;
  o.x = f2b(tanhf(a.x)); o.y = f2b(tanhf(a.y));
  o.z = f2b(tanhf(a.z)); o.w = f2b(tanhf(a.w));
  ((ushort4*)out)[idx] = o;
}

// ---------------- batched gate GEMM (K=32): epilogue x + xx*(tm+acc) ----------------
struct GateArgs {
  const unsigned short* A;
  const unsigned short* Bt;
  unsigned short* out[4];
  const float* tm[4];
  const unsigned short* xb;
  const unsigned short* xxb;
};
__global__ __launch_bounds__(256) void gemm_gate4(GateArgs ga) {
  __shared__ __align__(16) unsigned short As[3 * 4096];
  __shared__ __align__(16) unsigned short Bs[3 * 4096];
  // 4 gates of the same (row,col) tile consecutive on one XCD (xb/xxb L2 reuse)
  int flat = (blockIdx.z * 64 + blockIdx.y) * 8 + blockIdx.x;
  int xcd = flat & 7;
  int idx = flat >> 3;
  int z = idx & 3;
  int tile = idx >> 2;
  int by = xcd * 8 + (tile >> 3);
  int bx = tile & 7;
  const unsigned short* A = ga.A + z * 32;
  const unsigned short* Bt = ga.Bt + (size_t)z * 1024 * 32;
  unsigned short* outB = ga.out[z];
  const float* tm = ga.tm[z];
  int tid = threadIdx.x;
  int w = tid >> 6, lane = tid & 63;
  int quad = lane >> 4, l16 = lane & 15;
  int rowBase = by * 128;
  int colBase = bx * 128;
  int waveM = (w >> 1) * 64, waveN = (w & 1) * 64;
  f32x4 acc[4][4];
  gemm_core_pipe(A, Bt, 0, 32, 128, 32, rowBase, colBase, As, Bs, acc, w, lane, quad, l16, waveM, waveN);
#pragma unroll
  for (int mt = 0; mt < 4; mt++)
#pragma unroll
    for (int nt = 0; nt < 4; nt++)
#pragma unroll
      for (int rg = 0; rg < 4; rg++) {
        int row = rowBase + waveM + mt * 16 + quad * 4 + rg;
        int col = colBase + waveN + nt * 16 + l16;
        size_t o = (size_t)row * CC + col;
        float xv = b2f(ga.xb[o]), xxv = b2f(ga.xxb[o]);
        outB[o] = f2b(xv + xxv * (tm[col] + acc[mt][nt][rg]));
      }
}

// ---------------- counted-vmcnt 256x128 core, templated slot depth (R16) ----------------
// R15 A/B result: slot-depth and occupancy trade off, PER KERNEL by blocks/CU:
//  - 2 blocks/CU resident (proj3: 768 blocks, 72KB): NSLOT=3 wins — independent
//    blocks' barriers decorrelate; one block's MFMA fills the other's drain
//    (measured 66.4 -> 61.0us, MfmaUtil 36%, occ 32%).
//  - 1 block/CU (wo: 256 blocks): NSLOT=4 wins — no co-resident block, so the
//    deeper pipeline (9 outstanding loads vs 6) must cover latency internally
//    (NSLOT=3 + reg-squeeze regressed wo ~21 -> ~37us in R15).
// Steady-state wait: vmcnt(3*(NSLOT-2)) after staging h+NSLOT-1 (own-wave
// outstanding = 3*(NSLOT-1) loads, need half h+1 resident). lgkmcnt(0) closes
// the in-flight-ds_read vs slot-overwrite window (rule #18).
template <int NSLOT>
__device__ __forceinline__ void core256x128(
    const unsigned short* __restrict__ A, const unsigned short* __restrict__ Bt,
    int rowBase, int colBase, unsigned short* As, unsigned short* Bs,
    f32x4 acc[4][4]) {
  int tid = threadIdx.x;
  int w = tid >> 6, lane = tid & 63;
  int quad = lane >> 4, l16 = lane & 15;
  int wr = w >> 1, wc = w & 1;
  int rl = lane >> 2;
  int cl = (lane & 3) ^ ((lane >> 3) & 3);
  const unsigned short* gA0 = A + (size_t)(rowBase + w * 16 + rl) * 1024 + cl * 8;
  const unsigned short* gA1 = A + (size_t)(rowBase + (w + 8) * 16 + rl) * 1024 + cl * 8;
  const unsigned short* gB0 = Bt + (size_t)(colBase + w * 16 + rl) * 1024 + cl * 8;
  char* dA0 = (char*)As + w * 1024;
  char* dA1 = (char*)As + (w + 8) * 1024;
  char* dB0 = (char*)Bs + w * 1024;
  int sw = quad ^ ((l16 >> 1) & 3);
  int aoffB = wr * 4096 + l16 * 64 + sw * 16;
  int boffB = wc * 4096 + l16 * 64 + sw * 16;
#pragma unroll
  for (int i = 0; i < 4; i++)
#pragma unroll
    for (int j = 0; j < 4; j++) acc[i][j] = (f32x4){0.f, 0.f, 0.f, 0.f};

#define STG(h, st)                                        \
  { int kc = (h) * 32;                                    \
    int slA = (st) * 16384, slB = (st) * 8192;            \
    gl_lds16(gA0 + kc, dA0 + slA);                        \
    gl_lds16(gA1 + kc, dA1 + slA);                        \
    gl_lds16(gB0 + kc, dB0 + slB); }

  if constexpr (NSLOT == 4) {
    STG(0, 0) STG(1, 1) STG(2, 2)
    asm volatile("s_waitcnt vmcnt(6)\ns_barrier" ::: "memory");  // half 0 landed
  } else {
    STG(0, 0) STG(1, 1)
    asm volatile("s_waitcnt vmcnt(3)\ns_barrier" ::: "memory");  // half 0 landed
  }

  int sl = 0;
  for (int h = 0; h < 32; ++h) {
    const char* Ab = (const char*)As + sl * 16384;
    const char* Bb = (const char*)Bs + sl * 8192;
    bf16x8 af[4], bfr[4];
#pragma unroll
    for (int nt = 0; nt < 4; nt++)
      bfr[nt] = *(const bf16x8*)(Bb + boffB + nt * 1024);
#pragma unroll
    for (int mt = 0; mt < 4; mt++)
      af[mt] = *(const bf16x8*)(Ab + aoffB + mt * 1024);
    if (h + NSLOT - 1 < 32) {
      int ns = sl + NSLOT - 1; if (ns >= NSLOT) ns -= NSLOT;
      STG(h + NSLOT - 1, ns)
    }
    __builtin_amdgcn_s_setprio(1);
#pragma unroll
    for (int mt = 0; mt < 4; mt++)
#pragma unroll
      for (int nt = 0; nt < 4; nt++)
        acc[mt][nt] = __builtin_amdgcn_mfma_f32_16x16x32_bf16(af[mt], bfr[nt], acc[mt][nt], 0, 0, 0);
    __builtin_amdgcn_s_setprio(0);
    // counted wait (own-wave loads), then barrier publishes all waves' halves.
    if constexpr (NSLOT == 4) {
      if (h <= 28) {
        asm volatile("s_waitcnt vmcnt(6) lgkmcnt(0)\ns_barrier" ::: "memory");
      } else if (h == 29) {
        asm volatile("s_waitcnt vmcnt(3) lgkmcnt(0)\ns_barrier" ::: "memory");
      } else if (h == 30) {
        asm volatile("s_waitcnt vmcnt(0) lgkmcnt(0)\ns_barrier" ::: "memory");
      }
    } else {
      if (h <= 29) {
        asm volatile("s_waitcnt vmcnt(3) lgkmcnt(0)\ns_barrier" ::: "memory");
      } else if (h == 30) {
        asm volatile("s_waitcnt vmcnt(0) lgkmcnt(0)\ns_barrier" ::: "memory");
      }
    }
    sl = sl + 1; if (sl >= NSLOT) sl = 0;
  }
#undef STG
}

// ---------------- projection GEMM (NSLOT=3, 2 blocks/CU) ----------------
struct ProjArgs {
  const unsigned short* A[3];
  const unsigned short* Bt[3];
  unsigned short* out[3];
};
__global__ __launch_bounds__(512, 4) void gemm_proj3_8ph(ProjArgs pa) {
  __shared__ __align__(16) unsigned short As[3 * 8192];  // 3 slots x 16KB
  __shared__ __align__(16) unsigned short Bs[3 * 4096];  // 3 slots x 8KB
  int bx, by, bz;
  swiz(bx, by, bz);
  f32x4 acc[4][4];
  core256x128<3>(pa.A[bz], pa.Bt[bz], by * 256, bx * 128, As, Bs, acc);
  unsigned short* outB = pa.out[bz];
  int tid = threadIdx.x;
  int w = tid >> 6, lane = tid & 63;
  int quad = lane >> 4, l16 = lane & 15;
  int wr = w >> 1, wc = w & 1;
#pragma unroll
  for (int mt = 0; mt < 4; mt++)
#pragma unroll
    for (int nt = 0; nt < 4; nt++)
#pragma unroll
      for (int rg = 0; rg < 4; rg++) {
        int row = by * 256 + wr * 64 + mt * 16 + quad * 4 + rg;
        int col = bx * 128 + wc * 64 + nt * 16 + l16;
        int b = row >> 11, t = row & (TT - 1), hh = col >> 4, n = col & 15;
        outB[(size_t)((b * 64 + hh) * TT + t) * 16 + n] = f2b(acc[mt][nt][rg]);
      }
}

// ---------------- Wo GEMM (NSLOT=4, 1 block/CU needs deep pipeline) ----------------
__global__ __launch_bounds__(512, 2) void gemm_wo_8ph(
    const unsigned short* __restrict__ A, const unsigned short* __restrict__ Bt,
    float* __restrict__ outF) {
  __shared__ __align__(16) unsigned short As[4 * 8192];
  __shared__ __align__(16) unsigned short Bs[4 * 4096];
  int bx, by, bz;
  swiz(bx, by, bz);
  (void)bz;
  f32x4 acc[4][4];
  core256x128<4>(A, Bt, by * 256, bx * 128, As, Bs, acc);
  int tid = threadIdx.x;
  int w = tid >> 6, lane = tid & 63;
  int quad = lane >> 4, l16 = lane & 15;
  int wr = w >> 1, wc = w & 1;
#pragma unroll
  for (int mt = 0; mt < 4; mt++)
#pragma unroll
    for (int nt = 0; nt < 4; nt++)
#pragma unroll
      for (int rg = 0; rg < 4; rg++) {
        int row = by * 256 + wr * 64 + mt * 16 + quad * 4 + rg;
        int col = bx * 128 + wc * 64 + nt * 16 + l16;
        outF[(size_t)row * CC + col] = acc[mt][nt][rg];
      }
}

// ---------------- WKV6 chunk-parallel scan (16 waves per (b,h)) ----------------
// R8 version (R13's direct-global traded DS pipe for per-step global LATENCY,
// 102us — LDS staging amortizes latency to one coalesced load per 16-step tile).
// (a) r/k/v bf16 in LDS (b64/u16 reads; conversions on idle VALU pipe);
//     w stays f32 (128-long decay product chain).
// (b) cross-p output reduction via permlane{32,16}_swap (VALU) not __shfl_xor
//     (DS). permlaneN_swap returns {new_d, new_s}; needed element is in .y.
__device__ __forceinline__ float reduce_p(float part) {
#if __has_builtin(__builtin_amdgcn_permlane32_swap) && __has_builtin(__builtin_amdgcn_permlane16_swap)
  uint2v a = __builtin_amdgcn_permlane32_swap(__float_as_uint(part), __float_as_uint(part), false, false);
  float s1 = part + __uint_as_float(a.y);
  uint2v b = __builtin_amdgcn_permlane16_swap(__float_as_uint(s1), __float_as_uint(s1), false, false);
  return s1 + __uint_as_float(b.y);
#else
  part += __shfl_xor(part, 16, 64);
  part += __shfl_xor(part, 32, 64);
  return part;
#endif
}

__global__ __launch_bounds__(1024) void wkv_scan2(
    const unsigned short* __restrict__ r, const unsigned short* __restrict__ k,
    const unsigned short* __restrict__ v, const float* __restrict__ wd,
    const float* __restrict__ u, float* __restrict__ y) {
  __shared__ __align__(16) unsigned short lrb[16][256];
  __shared__ __align__(16) unsigned short lkb[16][256];
  __shared__ __align__(16) unsigned short lvb[16][256];
  __shared__ __align__(16) float lw[16][256];
  __shared__ __align__(16) float Lend[16][256];
  __shared__ __align__(16) float Sini[16][256];
  __shared__ float Eend[16][16];
  int bh = blockIdx.x;
  int b = bh >> 6, h = bh & 63;
  int tid = threadIdx.x;
  int c = tid >> 6, lane = tid & 63;
  int j = lane & 15, p = lane >> 4;
  size_t base = (size_t)bh * TT * 16 + (size_t)c * 128 * 16;

  float S0 = 0.f, S1 = 0.f, S2 = 0.f, S3 = 0.f;
  float E0 = 1.f, E1 = 1.f, E2 = 1.f, E3 = 1.f;
  for (int t0 = 0; t0 < 128; t0 += 16) {
    size_t off = base + (size_t)t0 * 16;
    ushort4 kv4 = ((const ushort4*)(k + off))[lane];
    ushort4 vv = ((const ushort4*)(v + off))[lane];
    float4 wv = ((const float4*)(wd + off))[lane];
    ((ushort4*)lkb[c])[lane] = kv4;
    ((ushort4*)lvb[c])[lane] = vv;
    ((float4*)lw[c])[lane] = wv;
#pragma unroll
    for (int s = 0; s < 16; s++) {
      ushort4 kk = *(const ushort4*)(lkb[c] + s * 16 + p * 4);
      float4 ww = *(const float4*)(lw[c] + s * 16 + p * 4);
      float vj = b2f(lvb[c][s * 16 + j]);
      S0 = fmaf(ww.x, S0, b2f(kk.x) * vj); E0 *= ww.x;
      S1 = fmaf(ww.y, S1, b2f(kk.y) * vj); E1 *= ww.y;
      S2 = fmaf(ww.z, S2, b2f(kk.z) * vj); E2 *= ww.z;
      S3 = fmaf(ww.w, S3, b2f(kk.w) * vj); E3 *= ww.w;
    }
  }
  Lend[c][(p * 4 + 0) * 16 + j] = S0;
  Lend[c][(p * 4 + 1) * 16 + j] = S1;
  Lend[c][(p * 4 + 2) * 16 + j] = S2;
  Lend[c][(p * 4 + 3) * 16 + j] = S3;
  if (j == 0) {
    Eend[c][p * 4 + 0] = E0;
    Eend[c][p * 4 + 1] = E1;
    Eend[c][p * 4 + 2] = E2;
    Eend[c][p * 4 + 3] = E3;
  }
  __syncthreads();

  if (c == 0) {
    float T0 = 0.f, T1 = 0.f, T2 = 0.f, T3 = 0.f;
    for (int cc = 0; cc < 16; cc++) {
      Sini[cc][(p * 4 + 0) * 16 + j] = T0;
      Sini[cc][(p * 4 + 1) * 16 + j] = T1;
      Sini[cc][(p * 4 + 2) * 16 + j] = T2;
      Sini[cc][(p * 4 + 3) * 16 + j] = T3;
      float e0 = Eend[cc][p * 4 + 0], e1 = Eend[cc][p * 4 + 1];
      float e2 = Eend[cc][p * 4 + 2], e3 = Eend[cc][p * 4 + 3];
      T0 = fmaf(e0, T0, Lend[cc][(p * 4 + 0) * 16 + j]);
      T1 = fmaf(e1, T1, Lend[cc][(p * 4 + 1) * 16 + j]);
      T2 = fmaf(e2, T2, Lend[cc][(p * 4 + 2) * 16 + j]);
      T3 = fmaf(e3, T3, Lend[cc][(p * 4 + 3) * 16 + j]);
    }
  }
  __syncthreads();

  float u0 = u[h * 16 + p * 4 + 0], u1 = u[h * 16 + p * 4 + 1];
  float u2 = u[h * 16 + p * 4 + 2], u3 = u[h * 16 + p * 4 + 3];
  S0 = Sini[c][(p * 4 + 0) * 16 + j];
  S1 = Sini[c][(p * 4 + 1) * 16 + j];
  S2 = Sini[c][(p * 4 + 2) * 16 + j];
  S3 = Sini[c][(p * 4 + 3) * 16 + j];
  for (int t0 = 0; t0 < 128; t0 += 16) {
    size_t off = base + (size_t)t0 * 16;
    ushort4 rv = ((const ushort4*)(r + off))[lane];
    ushort4 kv4 = ((const ushort4*)(k + off))[lane];
    ushort4 vv = ((const ushort4*)(v + off))[lane];
    float4 wv = ((const float4*)(wd + off))[lane];
    ((ushort4*)lrb[c])[lane] = rv;
    ((ushort4*)lkb[c])[lane] = kv4;
    ((ushort4*)lvb[c])[lane] = vv;
    ((float4*)lw[c])[lane] = wv;
#pragma unroll
    for (int s = 0; s < 16; s++) {
      ushort4 rr4 = *(const ushort4*)(lrb[c] + s * 16 + p * 4);
      ushort4 kk4 = *(const ushort4*)(lkb[c] + s * 16 + p * 4);
      float4 ww = *(const float4*)(lw[c] + s * 16 + p * 4);
      float vj = b2f(lvb[c][s * 16 + j]);
      float kv, part;
      kv = b2f(kk4.x) * vj; part = b2f(rr4.x) * fmaf(u0, kv, S0); S0 = fmaf(ww.x, S0, kv);
      kv = b2f(kk4.y) * vj; part = fmaf(b2f(rr4.y), fmaf(u1, kv, S1), part); S1 = fmaf(ww.y, S1, kv);
      kv = b2f(kk4.z) * vj; part = fmaf(b2f(rr4.z), fmaf(u2, kv, S2), part); S2 = fmaf(ww.z, S2, kv);
      kv = b2f(kk4.w) * vj; part = fmaf(b2f(rr4.w), fmaf(u3, kv, S3), part); S3 = fmaf(ww.w, S3, kv);
      float tot = reduce_p(part);
      if (p == 0) y[(size_t)(b * TT + c * 128 + t0 + s) * CC + h * 16 + j] = tot;
    }
  }
}

// ---------------- LayerNorm -> bf16 ----------------
__global__ __launch_bounds__(256) void ln_fused(const float* __restrict__ y,
                                                const float* __restrict__ g,
                                                const float* __restrict__ be,
                                                unsigned short* __restrict__ out) {
  int row = blockIdx.x;
  int tid = threadIdx.x;
  float4 val = ((const float4*)(y + (size_t)row * CC))[tid];
  float s = val.x + val.y + val.z + val.w;
  float sq = val.x * val.x + val.y * val.y + val.z * val.z + val.w * val.w;
#pragma unroll
  for (int m = 1; m < 64; m <<= 1) {
    s += __shfl_xor(s, m, 64);
    sq += __shfl_xor(sq, m, 64);
  }
  __shared__ float ss[4], s2[4];
  int w = tid >> 6;
  if ((tid & 63) == 0) { ss[w] = s; s2[w] = sq; }
  __syncthreads();
  s = ss[0] + ss[1] + ss[2] + ss[3];
  sq = s2[0] + s2[1] + s2[2] + s2[3];
  float mu = s * (1.f / 1024.f);
  float var = sq * (1.f / 1024.f) - mu * mu;
  float rstd = rsqrtf(var + 1e-5f);
  float4 gg = ((const float4*)g)[tid];
  float4 bb = ((const float4*)be)[tid];
  ushort4 o;
  o.x = f2b((val.x - mu) * rstd * gg.x + bb.x);
  o.y = f2b((val.y - mu) * rstd * gg.y + bb.y);
  o.z = f2b((val.z - mu) * rstd * gg.z + bb.z);
  o.w = f2b((val.w - mu) * rstd * gg.w + bb.w);
  ((ushort4*)(out + (size_t)row * CC))[tid] = o;
}

extern "C" void kernel_launch(void* const* d_in, const int* in_sizes, int n_in,
                              void* d_out, int out_size, void* d_ws, size_t ws_size,
                              hipStream_t stream) {
  (void)in_sizes; (void)n_in; (void)out_size; (void)ws_size;
  const float* x = (const float*)d_in[0];
  const float* tmx = (const float*)d_in[1];
  const float* tmw = (const float*)d_in[2];
  const float* tmk = (const float*)d_in[3];
  const float* tmv = (const float*)d_in[4];
  const float* tmr = (const float*)d_in[5];
  const float* w1 = (const float*)d_in[6];
  const float* w2 = (const float*)d_in[7];
  const float* tdecay = (const float*)d_in[8];
  const float* dw1 = (const float*)d_in[9];
  const float* dw2 = (const float*)d_in[10];
  const float* faaaa = (const float*)d_in[11];
  const float* Wr = (const float*)d_in[12];
  const float* Wk = (const float*)d_in[13];
  const float* Wv = (const float*)d_in[14];
  const float* Wo = (const float*)d_in[15];
  const float* lng = (const float*)d_in[16];
  const float* lnb = (const float*)d_in[17];
  float* out = (float*)d_out;

  char* ws = (char*)d_ws;
  const size_t MBy = 1ull << 20;
  unsigned short* rb   = (unsigned short*)(ws + 0);        // 16MB bf16 [BH,T,16]
  unsigned short* kbuf = (unsigned short*)(ws + 16 * MBy); // 16MB
  unsigned short* vbuf = (unsigned short*)(ws + 32 * MBy); // 16MB
  float* wdb = (float*)(ws + 48 * MBy);                    // 32MB f32 [BH,T,16]
  unsigned short* xb    = (unsigned short*)(ws + 80 * MBy);  // 16MB (dead after gates)
  unsigned short* xxb16 = (unsigned short*)(ws + 96 * MBy);  // 16MB (dead after gates)
  float* yb = (float*)(ws + 80 * MBy);                       // 32MB, aliases xb+xxb16
  unsigned short* xxxb = (unsigned short*)(ws + 112 * MBy);  // 16MB (dead after mixer)
  unsigned short* xwb  = (unsigned short*)(ws + 112 * MBy);  // aliases xxx
  unsigned short* xrb  = (unsigned short*)(ws + 128 * MBy);  // 16MB
  unsigned short* xkb  = (unsigned short*)(ws + 144 * MBy);  // 16MB (dead after proj)
  unsigned short* ynb  = (unsigned short*)(ws + 144 * MBy);  // aliases xkb
  unsigned short* xvb  = (unsigned short*)(ws + 160 * MBy);  // 16MB
  // split-K partial scratch, placed in regions dead at their use time:
  float* mixP  = (float*)(ws + 128 * MBy);  // 16MB f32 [4][8192][128]; xrb written later
  float* decP  = (float*)(ws + 0);          // 8MB  f32 [4][8192][64];  rb written later
  unsigned short* mtmpb = (unsigned short*)(ws + 176 * MBy); // 2MB bf16 [8192,128]
  unsigned short* dtmpb = (unsigned short*)(ws + 178 * MBy); // 1MB bf16 [8192,64]
  char* wreg = ws + 179 * MBy;
  unsigned short* w1t  = (unsigned short*)(wreg);               // [128,1024]
  unsigned short* w2t  = (unsigned short*)(wreg + 256 * 1024);  // 4x[1024,32]
  unsigned short* dw1t = (unsigned short*)(wreg + 512 * 1024);  // [64,1024] (+pad reads ok)
  unsigned short* dw2t = (unsigned short*)(wreg + 768 * 1024);  // [1024,64]
  unsigned short* Wrt  = (unsigned short*)(wreg + 1024 * 1024); // [1024,1024]
  unsigned short* Wkt = Wrt + 1024 * 1024;
  unsigned short* Wvt = Wkt + 1024 * 1024;
  unsigned short* Wot = Wvt + 1024 * 1024;

  dim3 tb(32, 8);
  {
    TransAll ta;
    int st = 0, si = 0;
    auto add = [&](const float* in, unsigned short* o, int R, int C) {
      int tx = (C + 31) / 32, ty = (R + 31) / 32;
      ta.seg[si++] = TSeg{in, o, R, C, tx, st};
      st += tx * ty;
    };
    add(Wr, Wrt, 1024, 1024);
    add(Wk, Wkt, 1024, 1024);
    add(Wv, Wvt, 1024, 1024);
    add(Wo, Wot, 1024, 1024);
    for (int g = 0; g < 4; g++)
      add(w2 + (size_t)g * 32 * 1024, w2t + (size_t)g * 1024 * 32, 32, 1024);
    add(w1, w1t, 1024, 128);
    add(dw1, dw1t, 1024, 64);
    add(dw2, dw2t, 64, 1024);
    ta.nseg = si;
    transpose_all<<<st, tb, 0, stream>>>(ta);
  }

  shift_mix<<<8192, 256, 0, stream>>>(x, tmx, xb, xxb16, xxxb);

  // mixer: mtmp = tanh(xxx @ w1) via split-K(4)
  gemm_splitk<<<dim3(4, 64), 256, 0, stream>>>(xxxb, w1t, 128, 256, 1024, 1024, 128, mixP);
  reduce_tanh<<<1024, 256, 0, stream>>>(mixP, mtmpb, 8192 * 128 / 4, 4, 8192 * 128);

  // gates (batched): xg = bf16(x + xx*(tm_g + mtmp[:,g] @ w2[g]))
  {
    GateArgs ga;
    ga.A = mtmpb; ga.Bt = w2t;
    ga.out[0] = xwb; ga.out[1] = xkb; ga.out[2] = xvb; ga.out[3] = xrb;
    ga.tm[0] = tmw; ga.tm[1] = tmk; ga.tm[2] = tmv; ga.tm[3] = tmr;
    ga.xb = xb; ga.xxb = xxb16;
    gemm_gate4<<<dim3(8, 64, 4), 256, 0, stream>>>(ga);
  }
  // decay: dtmp = tanh(xw @ dw1) via split-K(4); wd = exp(-exp(tdecay + dtmp @ dw2))
  gemm_splitk<<<dim3(4, 64), 256, 0, stream>>>(xwb, dw1t, 64, 256, 1024, 1024, 64, decP);
  reduce_tanh<<<512, 256, 0, stream>>>(decP, dtmpb, 8192 * 64 / 4, 4, 8192 * 64);
  gemm_bf16<<<dim3(8, 64), 256, 0, stream>>>(dtmpb, dw2t, 1024, 64, 64, 64, 4, 1024,
                                             wdb, nullptr, tdecay);
  // projections (batched, permuted bf16 [BH,T,16]), 256x128 counted-vmcnt tiles,
  // 768 blocks; 3-slot LDS (72KB) -> 2 blocks/CU
  {
    ProjArgs pa;
    pa.A[0] = xrb; pa.A[1] = xkb; pa.A[2] = xvb;
    pa.Bt[0] = Wrt; pa.Bt[1] = Wkt; pa.Bt[2] = Wvt;
    pa.out[0] = rb; pa.out[1] = kbuf; pa.out[2] = vbuf;
    gemm_proj3_8ph<<<dim3(8, 32, 3), 512, 0, stream>>>(pa);
  }

  wkv_scan2<<<256, 1024, 0, stream>>>(rb, kbuf, vbuf, wdb, faaaa, yb);
  ln_fused<<<8192, 256, 0, stream>>>(yb, lng, lnb, ynb);
  // out = ynorm @ W_o (NSLOT=4 deep pipeline: 256 blocks = 1/CU, no partner block)
  gemm_wo_8ph<<<dim3(8, 32), 512, 0, stream>>>(ynb, Wot, out);
}

// Round 12
// 362.933 us; speedup vs baseline: 1.0504x; 1.0268x over previous
//
#include <hip/hip_runtime.h>
#include <stdint.h>

#define TT 2048
#define CC 1024

typedef short bf16x8 __attribute__((ext_vector_type(8)));
typedef float f32x4 __attribute__((ext_vector_type(4)));
typedef unsigned uint2v __attribute__((ext_vector_type(2)));
typedef __attribute__((address_space(3))) uint32_t lds_u32_t;
typedef const __attribute__((address_space(1))) uint32_t glb_u32_t;

__device__ inline unsigned short f2b(float f) {
  union { float f; unsigned u; } c; c.f = f;
  unsigned u = c.u;
  return (unsigned short)((u + 0x7fffu + ((u >> 16) & 1u)) >> 16);
}
__device__ inline float b2f(unsigned short s) {
  union { unsigned u; float f; } c; c.u = ((unsigned)s) << 16; return c.f;
}

__device__ inline void gl_lds16(const void* g, void* l) {
  glb_u32_t* gp = (glb_u32_t*)(uintptr_t)g;
  lds_u32_t* lp = (lds_u32_t*)(uint32_t)(uintptr_t)l;
  __builtin_amdgcn_global_load_lds(gp, lp, 16, 0, 0);
}

// XCD-aware swizzle (verified R3: FETCH 200->57MB on proj3). gridDim.y % 8 == 0.
__device__ inline void swiz(int& bx, int& by, int& bz) {
  int nx = gridDim.x, ny = gridDim.y;
  int flat = (blockIdx.z * ny + blockIdx.y) * nx + blockIdx.x;
  int xcd = flat & 7;
  int idx = flat >> 3;
  int perz = (nx * ny) >> 3;
  bz = idx / perz;
  int rem = idx - bz * perz;
  int r = rem / nx;
  bx = rem - r * nx;
  by = xcd * (ny >> 3) + r;
}

// ---------------- fused transposes: out[C,R] = bf16(in[R,C]), 11 segments ----------------
struct TSeg { const float* in; unsigned short* out; int R, C, tx, start; };
struct TransAll { TSeg seg[11]; int nseg; };
__global__ void transpose_all(TransAll ta) {
  __shared__ float tile[32][33];
  int bid = blockIdx.x;
  int si = 0;
  while (si + 1 < ta.nseg && bid >= ta.seg[si + 1].start) si++;
  TSeg sg = ta.seg[si];
  int lt = bid - sg.start;
  int bx = lt % sg.tx, by = lt / sg.tx;
  int c0 = bx * 32, r0 = by * 32;
  int tx = threadIdx.x, ty = threadIdx.y;  // 32x8
  for (int i = ty; i < 32; i += 8) {
    int r = r0 + i, c = c0 + tx;
    tile[i][tx] = (r < sg.R && c < sg.C) ? sg.in[(size_t)r * sg.C + c] : 0.f;
  }
  __syncthreads();
  int rr = r0 + tx;
  for (int i = ty; i < 32; i += 8) {
    int cc = c0 + i;
    if (cc < sg.C && rr < sg.R) sg.out[(size_t)cc * sg.R + rr] = f2b(tile[tx][i]);
  }
}

// ---- token shift: xb=bf16(x); xxb=bf16(shift(x)-x); xxx=bf16(x + xx*tmx) ----
__global__ void shift_mix(const float* __restrict__ x, const float* __restrict__ tmx,
                          unsigned short* __restrict__ xb, unsigned short* __restrict__ xxb,
                          unsigned short* __restrict__ xxx) {
  int idx = blockIdx.x * 256 + threadIdx.x;  // float4 groups, 2M total
  int c4 = idx & 255;
  int row = idx >> 8;
  int t = row & (TT - 1);
  const float4* x4 = (const float4*)x;
  float4 xv = x4[idx];
  float4 pv = make_float4(0.f, 0.f, 0.f, 0.f);
  if (t > 0) pv = x4[idx - 256];
  float4 d;
  d.x = pv.x - xv.x; d.y = pv.y - xv.y; d.z = pv.z - xv.z; d.w = pv.w - xv.w;
  ushort4 ob;
  ob.x = f2b(xv.x); ob.y = f2b(xv.y); ob.z = f2b(xv.z); ob.w = f2b(xv.w);
  ((ushort4*)xb)[idx] = ob;
  ushort4 od;
  od.x = f2b(d.x); od.y = f2b(d.y); od.z = f2b(d.z); od.w = f2b(d.w);
  ((ushort4*)xxb)[idx] = od;
  float4 tm = ((const float4*)tmx)[c4];
  ushort4 o;
  o.x = f2b(xv.x + d.x * tm.x);
  o.y = f2b(xv.y + d.y * tm.y);
  o.z = f2b(xv.z + d.z * tm.z);
  o.w = f2b(xv.w + d.w * tm.w);
  ((ushort4*)xxx)[idx] = o;
}

// ---------------- pipelined MFMA core A: 128x128 tile, BK=32, 3 LDS stages ----------------
// Used by gemm_bf16 (decay K=64), splitk, gate4. R10 lesson: this 2-barrier
// structure wants the 128^2 tile; bigger tiles only pay with the counted-vmcnt
// schedule (core256x128 below).
// COALESCED staging (R6): one gl_lds16 covers 16 rows x 64B (lane = row*4+chunk).
// LDS slot-chunk XOR-swizzled (chunk ^ ((row>>1)&3)); conflict-free (measured 0).
__device__ __forceinline__ void gemm_core_pipe(
    const unsigned short* __restrict__ A, const unsigned short* __restrict__ Bt,
    int k0beg, int k0end, int lda, int ldb, int rowBase, int colBase,
    unsigned short* As, unsigned short* Bs, f32x4 acc[4][4], int w, int lane,
    int quad, int l16, int waveM, int waveN) {
#pragma unroll
  for (int i = 0; i < 4; i++)
#pragma unroll
    for (int j = 0; j < 4; j++) acc[i][j] = (f32x4){0.f, 0.f, 0.f, 0.f};
  const int SSB = 8192;  // bytes per stage (128 rows x 64 B)
  const int nIter = (k0end - k0beg) >> 5;
  int rl = lane >> 2;
  int cl = (lane & 3) ^ ((lane >> 3) & 3);
  int rA0 = w * 16 + rl, rA1 = (w + 4) * 16 + rl;
  const unsigned short* gA0 = A + (size_t)(rowBase + rA0) * lda + cl * 8 + k0beg;
  const unsigned short* gA1 = A + (size_t)(rowBase + rA1) * lda + cl * 8 + k0beg;
  const unsigned short* gB0 = Bt + (size_t)(colBase + rA0) * ldb + cl * 8 + k0beg;
  const unsigned short* gB1 = Bt + (size_t)(colBase + rA1) * ldb + cl * 8 + k0beg;
  char* dA0 = (char*)As + w * 1024;
  char* dA1 = (char*)As + (w + 4) * 1024;
  char* dB0 = (char*)Bs + w * 1024;
  char* dB1 = (char*)Bs + (w + 4) * 1024;
  int sw = quad ^ ((l16 >> 1) & 3);
  int aoff = (waveM + l16) * 64 + sw * 16;
  int boff = (waveN + l16) * 64 + sw * 16;

#define ISSUE(it, st)                               \
  {                                                 \
    int ko = (it) * 32;                             \
    gl_lds16(gA0 + ko, dA0 + (st) * SSB);           \
    gl_lds16(gA1 + ko, dA1 + (st) * SSB);           \
    gl_lds16(gB0 + ko, dB0 + (st) * SSB);           \
    gl_lds16(gB1 + ko, dB1 + (st) * SSB);           \
  }

  ISSUE(0, 0)
  if (nIter > 1) ISSUE(1, 1)
  int stage = 0;
  for (int it = 0; it < nIter; ++it) {
    if (it + 1 < nIter) {
      asm volatile("s_waitcnt vmcnt(4)\ns_barrier" ::: "memory");
    } else {
      asm volatile("s_waitcnt vmcnt(0)\ns_barrier" ::: "memory");
    }
    if (it + 2 < nIter) {
      int ns = stage + 2; if (ns >= 3) ns -= 3;
      ISSUE(it + 2, ns)
    }
    const char* Ab = (const char*)As + stage * SSB;
    const char* Bb = (const char*)Bs + stage * SSB;
    bf16x8 af[4], bfr[4];
#pragma unroll
    for (int mt = 0; mt < 4; mt++)
      af[mt] = *(const bf16x8*)(Ab + aoff + mt * 1024);
#pragma unroll
    for (int nt = 0; nt < 4; nt++)
      bfr[nt] = *(const bf16x8*)(Bb + boff + nt * 1024);
#pragma unroll
    for (int mt = 0; mt < 4; mt++)
#pragma unroll
      for (int nt = 0; nt < 4; nt++)
        acc[mt][nt] = __builtin_amdgcn_mfma_f32_16x16x32_bf16(af[mt], bfr[nt], acc[mt][nt], 0, 0, 0);
    stage = stage + 1; if (stage >= 3) stage -= 3;
  }
#undef ISSUE
}

// ---------------- generic GEMM (128x128 core): modes 0 f32, 4 decay perm ----------------
__global__ __launch_bounds__(256) void gemm_bf16(
    const unsigned short* __restrict__ A, const unsigned short* __restrict__ Bt,
    int N, int K, int lda, int ldb, int mode, int ldc,
    float* __restrict__ outF, unsigned short* __restrict__ outB,
    const float* __restrict__ tm) {
  __shared__ __align__(16) unsigned short As[3 * 4096];
  __shared__ __align__(16) unsigned short Bs[3 * 4096];
  int bx, by, bz;
  swiz(bx, by, bz);
  (void)bz;
  int tid = threadIdx.x;
  int w = tid >> 6, lane = tid & 63;
  int quad = lane >> 4, l16 = lane & 15;
  int rowBase = by * 128;
  int colBase = bx * 128;
  int waveM = (w >> 1) * 64, waveN = (w & 1) * 64;
  f32x4 acc[4][4];
  gemm_core_pipe(A, Bt, 0, K, lda, ldb, rowBase, colBase, As, Bs, acc, w, lane, quad, l16, waveM, waveN);
#pragma unroll
  for (int mt = 0; mt < 4; mt++)
#pragma unroll
    for (int nt = 0; nt < 4; nt++)
#pragma unroll
      for (int rg = 0; rg < 4; rg++) {
        int row = rowBase + waveM + mt * 16 + quad * 4 + rg;
        int col = colBase + waveN + nt * 16 + l16;
        if (col >= N) continue;
        float val = acc[mt][nt][rg];
        if (mode == 0) {
          outF[(size_t)row * ldc + col] = val;
        } else {
          int b = row >> 11, t = row & (TT - 1), h = col >> 4, n = col & 15;
          outF[(size_t)((b * 64 + h) * TT + t) * 16 + n] = expf(-expf(tm[col] + val));
        }
      }
}

// ---------------- split-K GEMM (128x128 core): partials f32 [S][M][ldp] ----------------
__global__ __launch_bounds__(256) void gemm_splitk(
    const unsigned short* __restrict__ A, const unsigned short* __restrict__ Bt,
    int N, int Kc, int lda, int ldb, int ldp, float* __restrict__ part) {
  __shared__ __align__(16) unsigned short As[3 * 4096];
  __shared__ __align__(16) unsigned short Bs[3 * 4096];
  int s = blockIdx.x, by = blockIdx.y;
  int M = gridDim.y * 128;
  int tid = threadIdx.x;
  int w = tid >> 6, lane = tid & 63;
  int quad = lane >> 4, l16 = lane & 15;
  int rowBase = by * 128;
  int waveM = (w >> 1) * 64, waveN = (w & 1) * 64;
  f32x4 acc[4][4];
  gemm_core_pipe(A, Bt, s * Kc, (s + 1) * Kc, lda, ldb, rowBase, 0, As, Bs, acc, w, lane, quad, l16, waveM, waveN);
  float* pb = part + (size_t)s * M * ldp;
#pragma unroll
  for (int mt = 0; mt < 4; mt++)
#pragma unroll
    for (int nt = 0; nt < 4; nt++)
#pragma unroll
      for (int rg = 0; rg < 4; rg++) {
        int row = rowBase + waveM + mt * 16 + quad * 4 + rg;
        int col = waveN + nt * 16 + l16;
        if (col < N) pb[(size_t)row * ldp + col] = acc[mt][nt][rg];
      }
}

// ---------------- reduce split-K partials + tanh -> bf16 ----------------
__global__ __launch_bounds__(256) void reduce_tanh(
    const float* __restrict__ part, unsigned short* __restrict__ out,
    int total4, int S, int strideElems) {
  int idx = blockIdx.x * 256 + threadIdx.x;
  if (idx >= total4) return;
  float4 a = ((const float4*)part)[idx];
  for (int s = 1; s < S; s++) {
    float4 b = ((const float4*)(part + (size_t)s * strideElems))[idx];
    a.x += b.x; a.y += b.y; a.z += b.z; a.w += b.w;
  }
  ushort4 o;
  o.x = f2b(tanhf(a.x)); o.y = f2b(tanhf(a.y));
  o.z = f2b(tanhf(a.z)); o.w = f2b(tanhf(a.w));
  ((ushort4*)out)[idx] = o;
}

// ---------------- batched gate GEMM (K=32): epilogue x + xx*(tm+acc) ----------------
struct GateArgs {
  const unsigned short* A;
  const unsigned short* Bt;
  unsigned short* out[4];
  const float* tm[4];
  const unsigned short* xb;
  const unsigned short* xxb;
};
__global__ __launch_bounds__(256) void gemm_gate4(GateArgs ga) {
  __shared__ __align__(16) unsigned short As[3 * 4096];
  __shared__ __align__(16) unsigned short Bs[3 * 4096];
  // 4 gates of the same (row,col) tile consecutive on one XCD (xb/xxb L2 reuse)
  int flat = (blockIdx.z * 64 + blockIdx.y) * 8 + blockIdx.x;
  int xcd = flat & 7;
  int idx = flat >> 3;
  int z = idx & 3;
  int tile = idx >> 2;
  int by = xcd * 8 + (tile >> 3);
  int bx = tile & 7;
  const unsigned short* A = ga.A + z * 32;
  const unsigned short* Bt = ga.Bt + (size_t)z * 1024 * 32;
  unsigned short* outB = ga.out[z];
  const float* tm = ga.tm[z];
  int tid = threadIdx.x;
  int w = tid >> 6, lane = tid & 63;
  int quad = lane >> 4, l16 = lane & 15;
  int rowBase = by * 128;
  int colBase = bx * 128;
  int waveM = (w >> 1) * 64, waveN = (w & 1) * 64;
  f32x4 acc[4][4];
  gemm_core_pipe(A, Bt, 0, 32, 128, 32, rowBase, colBase, As, Bs, acc, w, lane, quad, l16, waveM, waveN);
#pragma unroll
  for (int mt = 0; mt < 4; mt++)
#pragma unroll
    for (int nt = 0; nt < 4; nt++)
#pragma unroll
      for (int rg = 0; rg < 4; rg++) {
        int row = rowBase + waveM + mt * 16 + quad * 4 + rg;
        int col = colBase + waveN + nt * 16 + l16;
        size_t o = (size_t)row * CC + col;
        float xv = b2f(ga.xb[o]), xxv = b2f(ga.xxb[o]);
        outB[o] = f2b(xv + xxv * (tm[col] + acc[mt][nt][rg]));
      }
}

// ---------------- counted-vmcnt 256x128 core, templated slot depth (R16) ----------------
// R15 A/B result: slot-depth and occupancy trade off, PER KERNEL by blocks/CU:
//  - 2 blocks/CU resident (proj3: 768 blocks, 72KB): NSLOT=3 wins — independent
//    blocks' barriers decorrelate; one block's MFMA fills the other's drain.
//  - 1 block/CU (wo: 256 blocks): NSLOT=4 wins — deeper pipeline covers latency
//    internally (NSLOT=3 + reg-squeeze regressed wo ~21 -> ~37us in R15).
// lgkmcnt(0) closes the in-flight-ds_read vs slot-overwrite window (rule #18).
template <int NSLOT>
__device__ __forceinline__ void core256x128(
    const unsigned short* __restrict__ A, const unsigned short* __restrict__ Bt,
    int rowBase, int colBase, unsigned short* As, unsigned short* Bs,
    f32x4 acc[4][4]) {
  int tid = threadIdx.x;
  int w = tid >> 6, lane = tid & 63;
  int quad = lane >> 4, l16 = lane & 15;
  int wr = w >> 1, wc = w & 1;
  int rl = lane >> 2;
  int cl = (lane & 3) ^ ((lane >> 3) & 3);
  const unsigned short* gA0 = A + (size_t)(rowBase + w * 16 + rl) * 1024 + cl * 8;
  const unsigned short* gA1 = A + (size_t)(rowBase + (w + 8) * 16 + rl) * 1024 + cl * 8;
  const unsigned short* gB0 = Bt + (size_t)(colBase + w * 16 + rl) * 1024 + cl * 8;
  char* dA0 = (char*)As + w * 1024;
  char* dA1 = (char*)As + (w + 8) * 1024;
  char* dB0 = (char*)Bs + w * 1024;
  int sw = quad ^ ((l16 >> 1) & 3);
  int aoffB = wr * 4096 + l16 * 64 + sw * 16;
  int boffB = wc * 4096 + l16 * 64 + sw * 16;
#pragma unroll
  for (int i = 0; i < 4; i++)
#pragma unroll
    for (int j = 0; j < 4; j++) acc[i][j] = (f32x4){0.f, 0.f, 0.f, 0.f};

#define STG(h, st)                                        \
  { int kc = (h) * 32;                                    \
    int slA = (st) * 16384, slB = (st) * 8192;            \
    gl_lds16(gA0 + kc, dA0 + slA);                        \
    gl_lds16(gA1 + kc, dA1 + slA);                        \
    gl_lds16(gB0 + kc, dB0 + slB); }

  if constexpr (NSLOT == 4) {
    STG(0, 0) STG(1, 1) STG(2, 2)
    asm volatile("s_waitcnt vmcnt(6)\ns_barrier" ::: "memory");  // half 0 landed
  } else {
    STG(0, 0) STG(1, 1)
    asm volatile("s_waitcnt vmcnt(3)\ns_barrier" ::: "memory");  // half 0 landed
  }

  int sl = 0;
  for (int h = 0; h < 32; ++h) {
    const char* Ab = (const char*)As + sl * 16384;
    const char* Bb = (const char*)Bs + sl * 8192;
    bf16x8 af[4], bfr[4];
#pragma unroll
    for (int nt = 0; nt < 4; nt++)
      bfr[nt] = *(const bf16x8*)(Bb + boffB + nt * 1024);
#pragma unroll
    for (int mt = 0; mt < 4; mt++)
      af[mt] = *(const bf16x8*)(Ab + aoffB + mt * 1024);
    if (h + NSLOT - 1 < 32) {
      int ns = sl + NSLOT - 1; if (ns >= NSLOT) ns -= NSLOT;
      STG(h + NSLOT - 1, ns)
    }
    __builtin_amdgcn_s_setprio(1);
#pragma unroll
    for (int mt = 0; mt < 4; mt++)
#pragma unroll
      for (int nt = 0; nt < 4; nt++)
        acc[mt][nt] = __builtin_amdgcn_mfma_f32_16x16x32_bf16(af[mt], bfr[nt], acc[mt][nt], 0, 0, 0);
    __builtin_amdgcn_s_setprio(0);
    // counted wait (own-wave loads), then barrier publishes all waves' halves.
    if constexpr (NSLOT == 4) {
      if (h <= 28) {
        asm volatile("s_waitcnt vmcnt(6) lgkmcnt(0)\ns_barrier" ::: "memory");
      } else if (h == 29) {
        asm volatile("s_waitcnt vmcnt(3) lgkmcnt(0)\ns_barrier" ::: "memory");
      } else if (h == 30) {
        asm volatile("s_waitcnt vmcnt(0) lgkmcnt(0)\ns_barrier" ::: "memory");
      }
    } else {
      if (h <= 29) {
        asm volatile("s_waitcnt vmcnt(3) lgkmcnt(0)\ns_barrier" ::: "memory");
      } else if (h == 30) {
        asm volatile("s_waitcnt vmcnt(0) lgkmcnt(0)\ns_barrier" ::: "memory");
      }
    }
    sl = sl + 1; if (sl >= NSLOT) sl = 0;
  }
#undef STG
}

// ---------------- projection GEMM (NSLOT=3, 2 blocks/CU) ----------------
struct ProjArgs {
  const unsigned short* A[3];
  const unsigned short* Bt[3];
  unsigned short* out[3];
};
__global__ __launch_bounds__(512, 4) void gemm_proj3_8ph(ProjArgs pa) {
  __shared__ __align__(16) unsigned short As[3 * 8192];  // 3 slots x 16KB
  __shared__ __align__(16) unsigned short Bs[3 * 4096];  // 3 slots x 8KB
  int bx, by, bz;
  swiz(bx, by, bz);
  f32x4 acc[4][4];
  core256x128<3>(pa.A[bz], pa.Bt[bz], by * 256, bx * 128, As, Bs, acc);
  unsigned short* outB = pa.out[bz];
  int tid = threadIdx.x;
  int w = tid >> 6, lane = tid & 63;
  int quad = lane >> 4, l16 = lane & 15;
  int wr = w >> 1, wc = w & 1;
#pragma unroll
  for (int mt = 0; mt < 4; mt++)
#pragma unroll
    for (int nt = 0; nt < 4; nt++)
#pragma unroll
      for (int rg = 0; rg < 4; rg++) {
        int row = by * 256 + wr * 64 + mt * 16 + quad * 4 + rg;
        int col = bx * 128 + wc * 64 + nt * 16 + l16;
        int b = row >> 11, t = row & (TT - 1), hh = col >> 4, n = col & 15;
        outB[(size_t)((b * 64 + hh) * TT + t) * 16 + n] = f2b(acc[mt][nt][rg]);
      }
}

// ---------------- Wo GEMM (NSLOT=4, 1 block/CU needs deep pipeline) ----------------
__global__ __launch_bounds__(512, 2) void gemm_wo_8ph(
    const unsigned short* __restrict__ A, const unsigned short* __restrict__ Bt,
    float* __restrict__ outF) {
  __shared__ __align__(16) unsigned short As[4 * 8192];
  __shared__ __align__(16) unsigned short Bs[4 * 4096];
  int bx, by, bz;
  swiz(bx, by, bz);
  (void)bz;
  f32x4 acc[4][4];
  core256x128<4>(A, Bt, by * 256, bx * 128, As, Bs, acc);
  int tid = threadIdx.x;
  int w = tid >> 6, lane = tid & 63;
  int quad = lane >> 4, l16 = lane & 15;
  int wr = w >> 1, wc = w & 1;
#pragma unroll
  for (int mt = 0; mt < 4; mt++)
#pragma unroll
    for (int nt = 0; nt < 4; nt++)
#pragma unroll
      for (int rg = 0; rg < 4; rg++) {
        int row = by * 256 + wr * 64 + mt * 16 + quad * 4 + rg;
        int col = bx * 128 + wc * 64 + nt * 16 + l16;
        outF[(size_t)row * CC + col] = acc[mt][nt][rg];
      }
}

// ---------------- WKV6 chunk-parallel scan (16 waves per (b,h)) ----------------
// R18: wd back to f32 (R17's f16-w failed absmax 0.082>0.0703 — per-step rel err
// 2.4e-4 compounds along the 128-step decay chain and 16-chunk prefix to ~3%).
// y output stays bf16 (safe: pre-LN, quantization normalized away; halves y
// write + ln read traffic).
// R8 base: r/k/v bf16 in LDS; cross-p reduction via permlane (VALU not DS).
__device__ __forceinline__ float reduce_p(float part) {
#if __has_builtin(__builtin_amdgcn_permlane32_swap) && __has_builtin(__builtin_amdgcn_permlane16_swap)
  uint2v a = __builtin_amdgcn_permlane32_swap(__float_as_uint(part), __float_as_uint(part), false, false);
  float s1 = part + __uint_as_float(a.y);
  uint2v b = __builtin_amdgcn_permlane16_swap(__float_as_uint(s1), __float_as_uint(s1), false, false);
  return s1 + __uint_as_float(b.y);
#else
  part += __shfl_xor(part, 16, 64);
  part += __shfl_xor(part, 32, 64);
  return part;
#endif
}

__global__ __launch_bounds__(1024) void wkv_scan2(
    const unsigned short* __restrict__ r, const unsigned short* __restrict__ k,
    const unsigned short* __restrict__ v, const float* __restrict__ wd,
    const float* __restrict__ u, unsigned short* __restrict__ y) {
  __shared__ __align__(16) unsigned short lrb[16][256];
  __shared__ __align__(16) unsigned short lkb[16][256];
  __shared__ __align__(16) unsigned short lvb[16][256];
  __shared__ __align__(16) float lw[16][256];
  __shared__ __align__(16) float Lend[16][256];
  __shared__ __align__(16) float Sini[16][256];
  __shared__ float Eend[16][16];
  int bh = blockIdx.x;
  int b = bh >> 6, h = bh & 63;
  int tid = threadIdx.x;
  int c = tid >> 6, lane = tid & 63;
  int j = lane & 15, p = lane >> 4;
  size_t base = (size_t)bh * TT * 16 + (size_t)c * 128 * 16;

  float S0 = 0.f, S1 = 0.f, S2 = 0.f, S3 = 0.f;
  float E0 = 1.f, E1 = 1.f, E2 = 1.f, E3 = 1.f;
  for (int t0 = 0; t0 < 128; t0 += 16) {
    size_t off = base + (size_t)t0 * 16;
    ushort4 kv4 = ((const ushort4*)(k + off))[lane];
    ushort4 vv = ((const ushort4*)(v + off))[lane];
    float4 wv = ((const float4*)(wd + off))[lane];
    ((ushort4*)lkb[c])[lane] = kv4;
    ((ushort4*)lvb[c])[lane] = vv;
    ((float4*)lw[c])[lane] = wv;
#pragma unroll
    for (int s = 0; s < 16; s++) {
      ushort4 kk = *(const ushort4*)(lkb[c] + s * 16 + p * 4);
      float4 ww = *(const float4*)(lw[c] + s * 16 + p * 4);
      float vj = b2f(lvb[c][s * 16 + j]);
      S0 = fmaf(ww.x, S0, b2f(kk.x) * vj); E0 *= ww.x;
      S1 = fmaf(ww.y, S1, b2f(kk.y) * vj); E1 *= ww.y;
      S2 = fmaf(ww.z, S2, b2f(kk.z) * vj); E2 *= ww.z;
      S3 = fmaf(ww.w, S3, b2f(kk.w) * vj); E3 *= ww.w;
    }
  }
  Lend[c][(p * 4 + 0) * 16 + j] = S0;
  Lend[c][(p * 4 + 1) * 16 + j] = S1;
  Lend[c][(p * 4 + 2) * 16 + j] = S2;
  Lend[c][(p * 4 + 3) * 16 + j] = S3;
  if (j == 0) {
    Eend[c][p * 4 + 0] = E0;
    Eend[c][p * 4 + 1] = E1;
    Eend[c][p * 4 + 2] = E2;
    Eend[c][p * 4 + 3] = E3;
  }
  __syncthreads();

  if (c == 0) {
    float T0 = 0.f, T1 = 0.f, T2 = 0.f, T3 = 0.f;
    for (int cc = 0; cc < 16; cc++) {
      Sini[cc][(p * 4 + 0) * 16 + j] = T0;
      Sini[cc][(p * 4 + 1) * 16 + j] = T1;
      Sini[cc][(p * 4 + 2) * 16 + j] = T2;
      Sini[cc][(p * 4 + 3) * 16 + j] = T3;
      float e0 = Eend[cc][p * 4 + 0], e1 = Eend[cc][p * 4 + 1];
      float e2 = Eend[cc][p * 4 + 2], e3 = Eend[cc][p * 4 + 3];
      T0 = fmaf(e0, T0, Lend[cc][(p * 4 + 0) * 16 + j]);
      T1 = fmaf(e1, T1, Lend[cc][(p * 4 + 1) * 16 + j]);
      T2 = fmaf(e2, T2, Lend[cc][(p * 4 + 2) * 16 + j]);
      T3 = fmaf(e3, T3, Lend[cc][(p * 4 + 3) * 16 + j]);
    }
  }
  __syncthreads();

  float u0 = u[h * 16 + p * 4 + 0], u1 = u[h * 16 + p * 4 + 1];
  float u2 = u[h * 16 + p * 4 + 2], u3 = u[h * 16 + p * 4 + 3];
  S0 = Sini[c][(p * 4 + 0) * 16 + j];
  S1 = Sini[c][(p * 4 + 1) * 16 + j];
  S2 = Sini[c][(p * 4 + 2) * 16 + j];
  S3 = Sini[c][(p * 4 + 3) * 16 + j];
  for (int t0 = 0; t0 < 128; t0 += 16) {
    size_t off = base + (size_t)t0 * 16;
    ushort4 rv = ((const ushort4*)(r + off))[lane];
    ushort4 kv4 = ((const ushort4*)(k + off))[lane];
    ushort4 vv = ((const ushort4*)(v + off))[lane];
    float4 wv = ((const float4*)(wd + off))[lane];
    ((ushort4*)lrb[c])[lane] = rv;
    ((ushort4*)lkb[c])[lane] = kv4;
    ((ushort4*)lvb[c])[lane] = vv;
    ((float4*)lw[c])[lane] = wv;
#pragma unroll
    for (int s = 0; s < 16; s++) {
      ushort4 rr4 = *(const ushort4*)(lrb[c] + s * 16 + p * 4);
      ushort4 kk4 = *(const ushort4*)(lkb[c] + s * 16 + p * 4);
      float4 ww = *(const float4*)(lw[c] + s * 16 + p * 4);
      float vj = b2f(lvb[c][s * 16 + j]);
      float kv, part;
      kv = b2f(kk4.x) * vj; part = b2f(rr4.x) * fmaf(u0, kv, S0); S0 = fmaf(ww.x, S0, kv);
      kv = b2f(kk4.y) * vj; part = fmaf(b2f(rr4.y), fmaf(u1, kv, S1), part); S1 = fmaf(ww.y, S1, kv);
      kv = b2f(kk4.z) * vj; part = fmaf(b2f(rr4.z), fmaf(u2, kv, S2), part); S2 = fmaf(ww.z, S2, kv);
      kv = b2f(kk4.w) * vj; part = fmaf(b2f(rr4.w), fmaf(u3, kv, S3), part); S3 = fmaf(ww.w, S3, kv);
      float tot = reduce_p(part);
      if (p == 0) y[(size_t)(b * TT + c * 128 + t0 + s) * CC + h * 16 + j] = f2b(tot);
    }
  }
}

// ---------------- LayerNorm (bf16 in) -> bf16 ----------------
__global__ __launch_bounds__(256) void ln_fused(const unsigned short* __restrict__ y,
                                                const float* __restrict__ g,
                                                const float* __restrict__ be,
                                                unsigned short* __restrict__ out) {
  int row = blockIdx.x;
  int tid = threadIdx.x;
  ushort4 vb = ((const ushort4*)(y + (size_t)row * CC))[tid];
  float4 val = make_float4(b2f(vb.x), b2f(vb.y), b2f(vb.z), b2f(vb.w));
  float s = val.x + val.y + val.z + val.w;
  float sq = val.x * val.x + val.y * val.y + val.z * val.z + val.w * val.w;
#pragma unroll
  for (int m = 1; m < 64; m <<= 1) {
    s += __shfl_xor(s, m, 64);
    sq += __shfl_xor(sq, m, 64);
  }
  __shared__ float ss[4], s2[4];
  int w = tid >> 6;
  if ((tid & 63) == 0) { ss[w] = s; s2[w] = sq; }
  __syncthreads();
  s = ss[0] + ss[1] + ss[2] + ss[3];
  sq = s2[0] + s2[1] + s2[2] + s2[3];
  float mu = s * (1.f / 1024.f);
  float var = sq * (1.f / 1024.f) - mu * mu;
  float rstd = rsqrtf(var + 1e-5f);
  float4 gg = ((const float4*)g)[tid];
  float4 bb = ((const float4*)be)[tid];
  ushort4 o;
  o.x = f2b((val.x - mu) * rstd * gg.x + bb.x);
  o.y = f2b((val.y - mu) * rstd * gg.y + bb.y);
  o.z = f2b((val.z - mu) * rstd * gg.z + bb.z);
  o.w = f2b((val.w - mu) * rstd * gg.w + bb.w);
  ((ushort4*)(out + (size_t)row * CC))[tid] = o;
}

extern "C" void kernel_launch(void* const* d_in, const int* in_sizes, int n_in,
                              void* d_out, int out_size, void* d_ws, size_t ws_size,
                              hipStream_t stream) {
  (void)in_sizes; (void)n_in; (void)out_size; (void)ws_size;
  const float* x = (const float*)d_in[0];
  const float* tmx = (const float*)d_in[1];
  const float* tmw = (const float*)d_in[2];
  const float* tmk = (const float*)d_in[3];
  const float* tmv = (const float*)d_in[4];
  const float* tmr = (const float*)d_in[5];
  const float* w1 = (const float*)d_in[6];
  const float* w2 = (const float*)d_in[7];
  const float* tdecay = (const float*)d_in[8];
  const float* dw1 = (const float*)d_in[9];
  const float* dw2 = (const float*)d_in[10];
  const float* faaaa = (const float*)d_in[11];
  const float* Wr = (const float*)d_in[12];
  const float* Wk = (const float*)d_in[13];
  const float* Wv = (const float*)d_in[14];
  const float* Wo = (const float*)d_in[15];
  const float* lng = (const float*)d_in[16];
  const float* lnb = (const float*)d_in[17];
  float* out = (float*)d_out;

  char* ws = (char*)d_ws;
  const size_t MBy = 1ull << 20;
  unsigned short* rb   = (unsigned short*)(ws + 0);        // 16MB bf16 [BH,T,16]
  unsigned short* kbuf = (unsigned short*)(ws + 16 * MBy); // 16MB
  unsigned short* vbuf = (unsigned short*)(ws + 32 * MBy); // 16MB
  float* wdb = (float*)(ws + 48 * MBy);                    // 32MB f32 [BH,T,16]
  unsigned short* xb    = (unsigned short*)(ws + 80 * MBy);  // 16MB (dead after gates)
  unsigned short* xxb16 = (unsigned short*)(ws + 96 * MBy);  // 16MB (dead after gates)
  unsigned short* yb16 = (unsigned short*)(ws + 80 * MBy);   // 16MB bf16, aliases xb
  unsigned short* xxxb = (unsigned short*)(ws + 112 * MBy);  // 16MB (dead after mixer)
  unsigned short* xwb  = (unsigned short*)(ws + 112 * MBy);  // aliases xxx
  unsigned short* xrb  = (unsigned short*)(ws + 128 * MBy);  // 16MB
  unsigned short* xkb  = (unsigned short*)(ws + 144 * MBy);  // 16MB (dead after proj)
  unsigned short* ynb  = (unsigned short*)(ws + 144 * MBy);  // aliases xkb
  unsigned short* xvb  = (unsigned short*)(ws + 160 * MBy);  // 16MB
  // split-K partial scratch, placed in regions dead at their use time:
  float* mixP  = (float*)(ws + 128 * MBy);  // 16MB f32 [4][8192][128]; xrb written later
  float* decP  = (float*)(ws + 0);          // 8MB  f32 [4][8192][64];  rb written later
  unsigned short* mtmpb = (unsigned short*)(ws + 176 * MBy); // 2MB bf16 [8192,128]
  unsigned short* dtmpb = (unsigned short*)(ws + 178 * MBy); // 1MB bf16 [8192,64]
  char* wreg = ws + 179 * MBy;
  unsigned short* w1t  = (unsigned short*)(wreg);               // [128,1024]
  unsigned short* w2t  = (unsigned short*)(wreg + 256 * 1024);  // 4x[1024,32]
  unsigned short* dw1t = (unsigned short*)(wreg + 512 * 1024);  // [64,1024] (+pad reads ok)
  unsigned short* dw2t = (unsigned short*)(wreg + 768 * 1024);  // [1024,64]
  unsigned short* Wrt  = (unsigned short*)(wreg + 1024 * 1024); // [1024,1024]
  unsigned short* Wkt = Wrt + 1024 * 1024;
  unsigned short* Wvt = Wkt + 1024 * 1024;
  unsigned short* Wot = Wvt + 1024 * 1024;

  dim3 tb(32, 8);
  {
    TransAll ta;
    int st = 0, si = 0;
    auto add = [&](const float* in, unsigned short* o, int R, int C) {
      int tx = (C + 31) / 32, ty = (R + 31) / 32;
      ta.seg[si++] = TSeg{in, o, R, C, tx, st};
      st += tx * ty;
    };
    add(Wr, Wrt, 1024, 1024);
    add(Wk, Wkt, 1024, 1024);
    add(Wv, Wvt, 1024, 1024);
    add(Wo, Wot, 1024, 1024);
    for (int g = 0; g < 4; g++)
      add(w2 + (size_t)g * 32 * 1024, w2t + (size_t)g * 1024 * 32, 32, 1024);
    add(w1, w1t, 1024, 128);
    add(dw1, dw1t, 1024, 64);
    add(dw2, dw2t, 64, 1024);
    ta.nseg = si;
    transpose_all<<<st, tb, 0, stream>>>(ta);
  }

  shift_mix<<<8192, 256, 0, stream>>>(x, tmx, xb, xxb16, xxxb);

  // mixer: mtmp = tanh(xxx @ w1) via split-K(4)
  gemm_splitk<<<dim3(4, 64), 256, 0, stream>>>(xxxb, w1t, 128, 256, 1024, 1024, 128, mixP);
  reduce_tanh<<<1024, 256, 0, stream>>>(mixP, mtmpb, 8192 * 128 / 4, 4, 8192 * 128);

  // gates (batched): xg = bf16(x + xx*(tm_g + mtmp[:,g] @ w2[g]))
  {
    GateArgs ga;
    ga.A = mtmpb; ga.Bt = w2t;
    ga.out[0] = xwb; ga.out[1] = xkb; ga.out[2] = xvb; ga.out[3] = xrb;
    ga.tm[0] = tmw; ga.tm[1] = tmk; ga.tm[2] = tmv; ga.tm[3] = tmr;
    ga.xb = xb; ga.xxb = xxb16;
    gemm_gate4<<<dim3(8, 64, 4), 256, 0, stream>>>(ga);
  }
  // decay: dtmp = tanh(xw @ dw1) via split-K(4); wd = exp(-exp(tdecay + dtmp @ dw2))
  gemm_splitk<<<dim3(4, 64), 256, 0, stream>>>(xwb, dw1t, 64, 256, 1024, 1024, 64, decP);
  reduce_tanh<<<512, 256, 0, stream>>>(decP, dtmpb, 8192 * 64 / 4, 4, 8192 * 64);
  gemm_bf16<<<dim3(8, 64), 256, 0, stream>>>(dtmpb, dw2t, 1024, 64, 64, 64, 4, 1024,
                                             wdb, nullptr, tdecay);
  // projections (batched, permuted bf16 [BH,T,16]), 256x128 counted-vmcnt tiles,
  // 768 blocks; 3-slot LDS (72KB) -> 2 blocks/CU
  {
    ProjArgs pa;
    pa.A[0] = xrb; pa.A[1] = xkb; pa.A[2] = xvb;
    pa.Bt[0] = Wrt; pa.Bt[1] = Wkt; pa.Bt[2] = Wvt;
    pa.out[0] = rb; pa.out[1] = kbuf; pa.out[2] = vbuf;
    gemm_proj3_8ph<<<dim3(8, 32, 3), 512, 0, stream>>>(pa);
  }

  wkv_scan2<<<256, 1024, 0, stream>>>(rb, kbuf, vbuf, wdb, faaaa, yb16);
  ln_fused<<<8192, 256, 0, stream>>>(yb16, lng, lnb, ynb);
  // out = ynorm @ W_o (NSLOT=4 deep pipeline: 256 blocks = 1/CU, no partner block)
  gemm_wo_8ph<<<dim3(8, 32), 512, 0, stream>>>(ynb, Wot, out);
}